// Round 5
// baseline (234.835 us; speedup 1.0000x reference)
//
#include <hip/hip_runtime.h>
#include <math.h>

// Problem constants (reference: T,B,E,H = 1024,4,1024,16; DH=64; 32 buckets, max_dist 128)
#define T_ 1024
#define B_ 4
#define E_ 1024
#define H_ 16
#define DH_ 64

#define LOG2E 1.44269504088896f

typedef __attribute__((ext_vector_type(8))) __bf16 bf16x8;
typedef __attribute__((ext_vector_type(4))) __bf16 bf16x4;
typedef __attribute__((ext_vector_type(4))) float f32x4;

// fp32 -> bf16 round-to-nearest-even
__device__ __forceinline__ __bf16 f2bf(float x){
  union { unsigned short u; __bf16 b; } cv;
  unsigned u32 = __float_as_uint(x);
  cv.u = (unsigned short)((u32 + 0x7fffu + ((u32 >> 16) & 1u)) >> 16);
  return cv.b;
}
// fp32 -> bf16 round-half-up (cheaper; used only for P >= 0)
__device__ __forceinline__ __bf16 f2bf_fast(float x){
  union { unsigned short u; __bf16 b; } cv;
  cv.u = (unsigned short)((__float_as_uint(x) + 0x8000u) >> 16);
  return cv.b;
}

// async global->LDS, 16B per lane; LDS dest is wave-uniform base + lane*16 (m97/m104)
__device__ __forceinline__ void glds16(const void* g, void* l){
  __builtin_amdgcn_global_load_lds(
      (__attribute__((address_space(1))) void*)(void*)g,
      (__attribute__((address_space(3))) void*)l,
      16, 0, 0);
}

// ---------------- prep: weight cvt (blocks 0..4095) + gates/qbf (4096..4351) + tab (4352..4479) ----------------
__global__ __launch_bounds__(256) void prep_kernel(
    const float* __restrict__ q_w, const float* __restrict__ k_w,
    const float* __restrict__ v_w, const float* __restrict__ out_w,
    __bf16* __restrict__ wq, __bf16* __restrict__ wk,
    __bf16* __restrict__ wv, __bf16* __restrict__ wo,
    const float* __restrict__ query, const float* __restrict__ gw,
    const float* __restrict__ gb, const float* __restrict__ ga,
    float* __restrict__ gates, __bf16* __restrict__ qbf,
    const float* __restrict__ rel_bias, __bf16* __restrict__ tab)
{
  const int bid = blockIdx.x;
  const int tid = threadIdx.x;
  if (bid < 4096){
    // ---- weight fp32->bf16: 4 matrices x 1M elems ----
    const float* a; __bf16* o;
    switch (bid >> 10){
      case 0: a = q_w;  o = wq; break;
      case 1: a = k_w;  o = wk; break;
      case 2: a = v_w;  o = wv; break;
      default: a = out_w; o = wo; break;
    }
    int i = ((bid & 1023) * 256 + tid) * 4;
    float4 v = *(const float4*)(a + i);
    bf16x4 r;
    r[0] = f2bf(v.x); r[1] = f2bf(v.y); r[2] = f2bf(v.z); r[3] = f2bf(v.w);
    *(bf16x4*)(o + i) = r;
  } else if (bid < 4352){
    // ---- gates + query bf16: wave = one t-row (64 lanes = 64 bh) ----
    int t = (bid - 4096) * 4 + (tid >> 6);
    int bh = tid & 63;
    int h = bh & 15;
    const float* q = query + (size_t)t * E_ * B_ + bh * 64;
    __bf16* qo = qbf + (size_t)t * E_ * B_ + bh * 64;
    float g[8];
    #pragma unroll
    for (int e = 0; e < 8; e++) g[e] = gb[e];
    #pragma unroll
    for (int c = 0; c < 8; c++){
      float4 v0 = *(const float4*)(q + c * 8);
      float4 v1 = *(const float4*)(q + c * 8 + 4);
      bf16x8 o;
      o[0] = f2bf(v0.x); o[1] = f2bf(v0.y); o[2] = f2bf(v0.z); o[3] = f2bf(v0.w);
      o[4] = f2bf(v1.x); o[5] = f2bf(v1.y); o[6] = f2bf(v1.z); o[7] = f2bf(v1.w);
      *(bf16x8*)(qo + c * 8) = o;
      #pragma unroll
      for (int e = 0; e < 8; e++){
        const float* w = gw + e * 64 + c * 8;     // uniform -> s_load
        g[e] += v0.x * w[0] + v0.y * w[1] + v0.z * w[2] + v0.w * w[3]
              + v1.x * w[4] + v1.y * w[5] + v1.z * w[6] + v1.w * w[7];
      }
    }
    float a0 = (g[0] + g[1]) + (g[2] + g[3]);
    float a1 = (g[4] + g[5]) + (g[6] + g[7]);
    float sa = 1.f / (1.f + __expf(-a0));
    float sb = 1.f / (1.f + __expf(-a1));
    gates[bh * T_ + t] = (sa * (sb * ga[h] - 1.0f) + 2.0f) * LOG2E;   // pre-scaled for exp2
  } else {
    // ---- rel-bias table: tab[h][rp+1023] (bf16) ----
    int tb = bid - 4352;               // 0..127
    int h = tb >> 3;
    int i = (tb & 7) * 256 + tid;
    if (i < 2047){
      int rp = i - 1023;
      int base = rp > 0 ? 16 : 0;
      int arp = rp < 0 ? -rp : rp;
      int off;
      if (arp < 8) off = arp;
      else {
        float val = (logf((float)arp * 0.125f) / 2.772588722239781f) * 8.0f;
        int lg = (int)val;
        off = 8 + (lg > 7 ? 7 : lg);
      }
      tab[h * 2047 + i] = f2bf(rel_bias[(base + off) * H_ + h]);
    }
  }
}

// ---------------- QKV GEMM: 128x128 tile, BK=64, XCD-swizzled 1-D grid (768) ----------------
// Per XCD: 4 m-slabs (1MB A, L2-resident) x all 24 (n,z). z=0/1 (q,k): scatter bf16 (B,H,T,DH);
// z=2 (v): LDS-transpose epilogue -> (B,H,DH,T) 64B-contiguous stores.
__global__ __launch_bounds__(256) void gemm_qkv(
    const __bf16* __restrict__ A,
    const __bf16* __restrict__ W0, const __bf16* __restrict__ W1, const __bf16* __restrict__ W2,
    const float* __restrict__ b0, const float* __restrict__ b1, const float* __restrict__ b2,
    __bf16* out0, __bf16* out1, __bf16* out2)
{
  __shared__ __bf16 smem[2][128 * 64];   // As/Bs (32 KB); reused for v-transpose epilogue
  __bf16* As = smem[0];
  __bf16* Bs = smem[1];
  const int tid = threadIdx.x;
  const int lane = tid & 63, wid = tid >> 6;
  const int l15 = lane & 15, quad = lane >> 4;
  const int wm = wid >> 1, wn = wid & 1;
  // XCD swizzle: xcd = d&7 owns m-slabs [xcd*4, xcd*4+4); j&3 = m fast, nz slow (W-slab reuse)
  const int dd = blockIdx.x;
  const int j = dd >> 3;
  const int m0 = ((dd & 7) * 4 + (j & 3)) * 128;
  const int nz = j >> 2;                 // 0..23
  const int n0 = (nz & 7) * 128;
  const int z = nz >> 3;

  const __bf16* W = W0;
  const float* bias = b0;
  float scale = 1.0f;
  __bf16* outp = out0;
  if (z == 0){ scale = 0.125f * LOG2E; }               // q: *DH^-0.5 * log2e
  else if (z == 1){ W = W1; bias = b1; outp = out1; }  // k
  else            { W = W2; bias = b2; outp = out2; }  // v

  f32x4 acc[4][4];
  #pragma unroll
  for (int i = 0; i < 4; i++)
    #pragma unroll
    for (int jj = 0; jj < 4; jj++){
      acc[i][jj][0] = 0.f; acc[i][jj][1] = 0.f; acc[i][jj][2] = 0.f; acc[i][jj][3] = 0.f;
    }

  const int grow = lane >> 3;           // 8 rows per glds16 round (64-elem rows)
  const int gcol = (lane & 7) * 8;

  for (int k0 = 0; k0 < E_; k0 += 64){
    __syncthreads();
    #pragma unroll
    for (int r = 0; r < 4; r++){
      int rb = wid * 32 + r * 8;        // wave covers rows [wid*32, wid*32+32)
      glds16(A + (size_t)(m0 + rb + grow) * E_ + k0 + gcol, &As[rb * 64]);
      glds16(W + (size_t)(n0 + rb + grow) * E_ + k0 + gcol, &Bs[rb * 64]);
    }
    __syncthreads();
    #pragma unroll
    for (int kq = 0; kq < 2; kq++){
      bf16x8 am[4], bn[4];
      #pragma unroll
      for (int i = 0; i < 4; i++) am[i] = *(const bf16x8*)&As[(wm * 64 + i * 16 + l15) * 64 + kq * 32 + quad * 8];
      #pragma unroll
      for (int jj = 0; jj < 4; jj++) bn[jj] = *(const bf16x8*)&Bs[(wn * 64 + jj * 16 + l15) * 64 + kq * 32 + quad * 8];
      #pragma unroll
      for (int i = 0; i < 4; i++)
        #pragma unroll
        for (int jj = 0; jj < 4; jj++)
          acc[i][jj] = __builtin_amdgcn_mfma_f32_16x16x32_bf16(am[i], bn[jj], acc[i][jj], 0, 0, 0);
    }
  }

  if (z != 2){
    // q/k epilogue: C/D layout col=lane&15, row=quad*4+reg (m89/m91); 32B-granule scatter
    #pragma unroll
    for (int i = 0; i < 4; i++){
      const int row0 = m0 + wm * 64 + i * 16 + quad * 4;
      #pragma unroll
      for (int jj = 0; jj < 4; jj++){
        const int col = n0 + wn * 64 + jj * 16 + l15;
        const float bc = bias[col];
        #pragma unroll
        for (int r = 0; r < 4; r++){
          float v = (acc[i][jj][r] + bc) * scale;
          int row = row0 + r;
          int t = row >> 2, bb = row & 3;       // m = t*B + b
          int hh = col >> 6, d2 = col & 63;     // n = h*DH + d
          outp[(size_t)((bb * H_ + hh) * T_ + t) * DH_ + d2] = f2bf(v);
        }
      }
    }
  } else {
    // v epilogue: transpose via LDS -> (B,H,DH,T); per-thread 64B-contiguous t-runs.
    __bf16 (*vbuf)[4][32] = (__bf16 (*)[4][32])&smem[0][0];   // [n_local(64)][bb(4)][t_local(32)]
    const int tb0 = m0 >> 2;
    #pragma unroll
    for (int p = 0; p < 2; p++){
      __syncthreads();
      if (wn == p){
        #pragma unroll
        for (int i = 0; i < 4; i++){
          const int t_local = wm * 16 + i * 4 + quad;
          #pragma unroll
          for (int jj = 0; jj < 4; jj++){
            const int nl = jj * 16 + l15;
            const float bc = bias[n0 + p * 64 + nl];
            #pragma unroll
            for (int r = 0; r < 4; r++)
              vbuf[nl][r][t_local] = f2bf(acc[i][jj][r] + bc);
          }
        }
      }
      __syncthreads();
      const int nl = tid >> 2;
      const int bb = tid & 3;
      const int colg = n0 + p * 64 + nl;
      const int hh = colg >> 6, d2 = colg & 63;
      __bf16* dst = outp + (size_t)((bb * H_ + hh) * DH_ + d2) * T_ + tb0;
      const __bf16* src = &vbuf[nl][bb][0];
      #pragma unroll
      for (int c = 0; c < 4; c++)
        *(bf16x8*)(dst + c * 8) = *(const bf16x8*)(src + c * 8);
    }
  }
}

// ---------------- out-proj GEMM: 64x128 tile, BK=64, XCD-swizzled 1-D grid (512), fp32 write ----------------
__global__ __launch_bounds__(256) void gemm_out(
    const __bf16* __restrict__ A, const __bf16* __restrict__ W,
    const float* __restrict__ bias, float* __restrict__ out)
{
  __shared__ __bf16 As[64 * 64];    // 8 KB
  __shared__ __bf16 Bs[128 * 64];   // 16 KB
  const int tid = threadIdx.x;
  const int lane = tid & 63, wid = tid >> 6;
  const int l15 = lane & 15, quad = lane >> 4;
  const int wm = wid >> 1, wn = wid & 1;
  // XCD swizzle: xcd owns 8 m-slabs (64 rows each); j&7 = m fast, n slow
  const int dd = blockIdx.x;
  const int j = dd >> 3;
  const int m0 = ((dd & 7) * 8 + (j & 7)) * 64;
  const int n0 = (j >> 3) * 128;

  f32x4 acc[2][4];
  #pragma unroll
  for (int i = 0; i < 2; i++)
    #pragma unroll
    for (int jj = 0; jj < 4; jj++){
      acc[i][jj][0] = 0.f; acc[i][jj][1] = 0.f; acc[i][jj][2] = 0.f; acc[i][jj][3] = 0.f;
    }

  const int grow = lane >> 3;
  const int gcol = (lane & 7) * 8;

  for (int k0 = 0; k0 < E_; k0 += 64){
    __syncthreads();
    #pragma unroll
    for (int r = 0; r < 2; r++){
      int rbA = wid * 16 + r * 8;     // As rows [wid*16, wid*16+16)
      glds16(A + (size_t)(m0 + rbA + grow) * E_ + k0 + gcol, &As[rbA * 64]);
    }
    #pragma unroll
    for (int r = 0; r < 4; r++){
      int rbB = wid * 32 + r * 8;     // Bs rows [wid*32, wid*32+32)
      glds16(W + (size_t)(n0 + rbB + grow) * E_ + k0 + gcol, &Bs[rbB * 64]);
    }
    __syncthreads();
    #pragma unroll
    for (int kq = 0; kq < 2; kq++){
      bf16x8 am[2], bn[4];
      #pragma unroll
      for (int i = 0; i < 2; i++) am[i] = *(const bf16x8*)&As[(wm * 32 + i * 16 + l15) * 64 + kq * 32 + quad * 8];
      #pragma unroll
      for (int jj = 0; jj < 4; jj++) bn[jj] = *(const bf16x8*)&Bs[(wn * 64 + jj * 16 + l15) * 64 + kq * 32 + quad * 8];
      #pragma unroll
      for (int i = 0; i < 2; i++)
        #pragma unroll
        for (int jj = 0; jj < 4; jj++)
          acc[i][jj] = __builtin_amdgcn_mfma_f32_16x16x32_bf16(am[i], bn[jj], acc[i][jj], 0, 0, 0);
    }
  }

  #pragma unroll
  for (int i = 0; i < 2; i++){
    const int row0 = m0 + wm * 32 + i * 16 + quad * 4;
    #pragma unroll
    for (int jj = 0; jj < 4; jj++){
      const int col = n0 + wn * 64 + jj * 16 + l15;
      const float bc = bias[col];
      #pragma unroll
      for (int r = 0; r < 4; r++)
        out[(size_t)(row0 + r) * E_ + col] = acc[i][jj][r] + bc;
    }
  }
}

// ---------------- flash attention: 128 t per block, 2 t-groups/wave, XCD-swizzled ----------------
__global__ __launch_bounds__(256) void attn_kernel(
    const __bf16* __restrict__ qg, const __bf16* __restrict__ kg, const __bf16* __restrict__ vgT,
    const float* __restrict__ gates, const __bf16* __restrict__ tab,
    __bf16* __restrict__ ctx)
{
  const int LD = 72;                   // 144B rows
  __shared__ __bf16 Ks[64 * LD];       // K-tile (s, d)
  __shared__ __bf16 Vt[64 * LD];       // V^T tile (d, s)
  __shared__ __bf16 Pt[4][2][16 * LD]; // per-wave, per-t-group P^T — wave-local, no barrier
  __shared__ __bf16 tabh[2048];

  const int tid = threadIdx.x;
  const int lane = tid & 63, wid = tid >> 6;
  const int l15 = lane & 15, quad = lane >> 4;
  const int dgrid = blockIdx.x;
  const int jj = dgrid >> 3;
  const int bh = (dgrid & 7) + 8 * (jj & 7);
  const int tq = jj >> 3;              // 0..3 -> t-base tq*128... (grid 512: jj 0..63, tq 0..7)
  const int b = bh >> 4, h = bh & 15;
  const __bf16* qb = qg + (size_t)bh * T_ * DH_;
  const __bf16* kb = kg + (size_t)bh * T_ * DH_;
  const __bf16* vb = vgT + (size_t)bh * DH_ * T_;

  for (int i = tid; i < 2047; i += 256) tabh[i] = tab[h * 2047 + i];

  const int t0w = tq * 128 + wid * 32; // wave owns 32 t = 2 groups of 16
  bf16x8 bq[2][2];
  float g[2];
  int ibase[2];
  #pragma unroll
  for (int tg = 0; tg < 2; tg++){
    int t_lane = t0w + tg * 16 + l15;
    bq[tg][0] = *(const bf16x8*)(qb + (size_t)t_lane * DH_ + quad * 8);
    bq[tg][1] = *(const bf16x8*)(qb + (size_t)t_lane * DH_ + 32 + quad * 8);
    g[tg] = gates[bh * T_ + t_lane];   // already * log2e
    ibase[tg] = 1023 - t_lane;
  }

  const int r0 = tid >> 3;
  const int c0 = (tid & 7) * 8;

  float l_run[2] = {0.f, 0.f};
  f32x4 O[2][4];
  #pragma unroll
  for (int tg = 0; tg < 2; tg++)
    #pragma unroll
    for (int mt = 0; mt < 4; mt++){ O[tg][mt][0]=0.f; O[tg][mt][1]=0.f; O[tg][mt][2]=0.f; O[tg][mt][3]=0.f; }

  bf16x8 kA = *(const bf16x8*)(kb + (size_t)r0 * DH_ + c0);
  bf16x8 kB = *(const bf16x8*)(kb + (size_t)(r0 + 32) * DH_ + c0);
  bf16x8 vA = *(const bf16x8*)(vb + (size_t)r0 * T_ + c0);
  bf16x8 vB = *(const bf16x8*)(vb + (size_t)(r0 + 32) * T_ + c0);

  for (int s0 = 0; s0 < T_; s0 += 64){
    __syncthreads();
    *(bf16x8*)&Ks[r0 * LD + c0] = kA;
    *(bf16x8*)&Ks[(r0 + 32) * LD + c0] = kB;
    *(bf16x8*)&Vt[r0 * LD + c0] = vA;
    *(bf16x8*)&Vt[(r0 + 32) * LD + c0] = vB;
    __syncthreads();

    int sn = (s0 + 64) & (T_ - 1);
    kA = *(const bf16x8*)(kb + (size_t)(sn + r0) * DH_ + c0);
    kB = *(const bf16x8*)(kb + (size_t)(sn + r0 + 32) * DH_ + c0);
    vA = *(const bf16x8*)(vb + (size_t)r0 * T_ + sn + c0);
    vB = *(const bf16x8*)(vb + (size_t)(r0 + 32) * T_ + sn + c0);

    // S^T = K.Q^T: A=K (shared across tg), B=Q^T. D: S^T[s=nt*16+quad*4+r][t=l15]
    f32x4 S[2][4];
    #pragma unroll
    for (int nt = 0; nt < 4; nt++){
      bf16x8 ak0 = *(const bf16x8*)&Ks[(nt * 16 + l15) * LD + quad * 8];
      bf16x8 ak1 = *(const bf16x8*)&Ks[(nt * 16 + l15) * LD + 32 + quad * 8];
      #pragma unroll
      for (int tg = 0; tg < 2; tg++){
        f32x4 a; a[0]=0.f; a[1]=0.f; a[2]=0.f; a[3]=0.f;
        a = __builtin_amdgcn_mfma_f32_16x16x32_bf16(ak0, bq[tg][0], a, 0, 0, 0);
        a = __builtin_amdgcn_mfma_f32_16x16x32_bf16(ak1, bq[tg][1], a, 0, 0, 0);
        S[tg][nt] = a;
      }
    }

    // bias + exp2 (no max-shift: scores O(10), fp32 exp2 safe; softmax shift-invariant)
    #pragma unroll
    for (int tg = 0; tg < 2; tg++){
      const int ib = ibase[tg] + s0;
      #pragma unroll
      for (int nt = 0; nt < 4; nt++)
        #pragma unroll
        for (int r = 0; r < 4; r++)
          S[tg][nt][r] = __builtin_amdgcn_exp2f(S[tg][nt][r] + g[tg] * (float)tabh[ib + nt * 16 + quad * 4 + r]);

      __bf16* pw = &Pt[wid][tg][0];
      #pragma unroll
      for (int nt = 0; nt < 4; nt++){
        bf16x4 p;
        p[0] = f2bf_fast(S[tg][nt][0]); p[1] = f2bf_fast(S[tg][nt][1]);
        p[2] = f2bf_fast(S[tg][nt][2]); p[3] = f2bf_fast(S[tg][nt][3]);
        *(bf16x4*)&pw[l15 * LD + nt * 16 + quad * 4] = p;
      }

      float rs = 0.f;
      #pragma unroll
      for (int nt = 0; nt < 4; nt++) rs += (S[tg][nt][0] + S[tg][nt][1]) + (S[tg][nt][2] + S[tg][nt][3]);
      rs += __shfl_xor(rs, 16, 64);
      rs += __shfl_xor(rs, 32, 64);
      l_run[tg] += rs;
    }

    // O^T += V^T.P^T: A=V^T (shared across tg), B=P^T
    #pragma unroll
    for (int ks = 0; ks < 2; ks++){
      bf16x8 bp[2];
      #pragma unroll
      for (int tg = 0; tg < 2; tg++)
        bp[tg] = *(const bf16x8*)&Pt[wid][tg][l15 * LD + ks * 32 + quad * 8];
      #pragma unroll
      for (int mt = 0; mt < 4; mt++){
        bf16x8 av = *(const bf16x8*)&Vt[(mt * 16 + l15) * LD + ks * 32 + quad * 8];
        #pragma unroll
        for (int tg = 0; tg < 2; tg++)
          O[tg][mt] = __builtin_amdgcn_mfma_f32_16x16x32_bf16(av, bp[tg], O[tg][mt], 0, 0, 0);
      }
    }
  }

  #pragma unroll
  for (int tg = 0; tg < 2; tg++){
    const int t_lane = t0w + tg * 16 + l15;
    const float inv = 1.f / l_run[tg];
    #pragma unroll
    for (int mt = 0; mt < 4; mt++){
      bf16x4 o;
      o[0] = f2bf(O[tg][mt][0] * inv); o[1] = f2bf(O[tg][mt][1] * inv);
      o[2] = f2bf(O[tg][mt][2] * inv); o[3] = f2bf(O[tg][mt][3] * inv);
      *(bf16x4*)&ctx[(size_t)(t_lane * B_ + b) * E_ + h * DH_ + mt * 16 + quad * 4] = o;
    }
  }
}

extern "C" void kernel_launch(void* const* d_in, const int* in_sizes, int n_in,
                              void* d_out, int out_size, void* d_ws, size_t ws_size,
                              hipStream_t stream)
{
  (void)in_sizes; (void)n_in; (void)out_size; (void)ws_size;
  const float* query    = (const float*)d_in[0];
  const float* q_w      = (const float*)d_in[1];
  const float* q_b      = (const float*)d_in[2];
  const float* k_w      = (const float*)d_in[3];
  const float* k_b      = (const float*)d_in[4];
  const float* v_w      = (const float*)d_in[5];
  const float* v_b      = (const float*)d_in[6];
  const float* out_w    = (const float*)d_in[7];
  const float* out_b    = (const float*)d_in[8];
  const float* rel_bias = (const float*)d_in[9];
  const float* grep_w   = (const float*)d_in[10];
  const float* grep_b   = (const float*)d_in[11];
  const float* grep_a   = (const float*)d_in[12];

  char* ws = (char*)d_ws;
  size_t off = 0;
  __bf16* qbf = (__bf16*)(ws + off); off += (size_t)4096 * 1024 * 2;   // query bf16 (TB, E)
  __bf16* wq  = (__bf16*)(ws + off); off += (size_t)1024 * 1024 * 2;
  __bf16* wk  = (__bf16*)(ws + off); off += (size_t)1024 * 1024 * 2;
  __bf16* wv  = (__bf16*)(ws + off); off += (size_t)1024 * 1024 * 2;
  __bf16* wo  = (__bf16*)(ws + off); off += (size_t)1024 * 1024 * 2;
  __bf16* qh  = (__bf16*)(ws + off); off += (size_t)4096 * 1024 * 2;   // (B,H,T,DH)
  __bf16* kh  = (__bf16*)(ws + off); off += (size_t)4096 * 1024 * 2;   // (B,H,T,DH)
  __bf16* vhT = (__bf16*)(ws + off); off += (size_t)4096 * 1024 * 2;   // (B,H,DH,T)
  __bf16* ctx = (__bf16*)(ws + off); off += (size_t)4096 * 1024 * 2;   // (TB, E)
  float* gates = (float*)(ws + off); off += (size_t)65536 * 4;         // (B*H, T), * log2e
  __bf16* tab  = (__bf16*)(ws + off); off += (size_t)16 * 2047 * 2;    // (H, 2047) bf16

  prep_kernel<<<4480, 256, 0, stream>>>(q_w, k_w, v_w, out_w, wq, wk, wv, wo,
                                        query, grep_w, grep_b, grep_a, gates, qbf,
                                        rel_bias, tab);
  gemm_qkv<<<768, 256, 0, stream>>>(qbf, wq, wk, wv, q_b, k_b, v_b, qh, kh, vhT);
  attn_kernel<<<512, 256, 0, stream>>>(qh, kh, vhT, gates, tab, ctx);
  gemm_out<<<512, 256, 0, stream>>>(ctx, wo, out_b, (float*)d_out);
}

// Round 6
// 221.583 us; speedup vs baseline: 1.0598x; 1.0598x over previous
//
#include <hip/hip_runtime.h>
#include <math.h>

// Problem constants (reference: T,B,E,H = 1024,4,1024,16; DH=64; 32 buckets, max_dist 128)
#define T_ 1024
#define B_ 4
#define E_ 1024
#define H_ 16
#define DH_ 64

#define LOG2E 1.44269504088896f

typedef __attribute__((ext_vector_type(8))) __bf16 bf16x8;
typedef __attribute__((ext_vector_type(4))) __bf16 bf16x4;
typedef __attribute__((ext_vector_type(4))) float f32x4;

// fp32 -> bf16 round-to-nearest-even
__device__ __forceinline__ __bf16 f2bf(float x){
  union { unsigned short u; __bf16 b; } cv;
  unsigned u32 = __float_as_uint(x);
  cv.u = (unsigned short)((u32 + 0x7fffu + ((u32 >> 16) & 1u)) >> 16);
  return cv.b;
}
// fp32 -> bf16 round-half-up (cheaper; used only for P >= 0)
__device__ __forceinline__ __bf16 f2bf_fast(float x){
  union { unsigned short u; __bf16 b; } cv;
  cv.u = (unsigned short)((__float_as_uint(x) + 0x8000u) >> 16);
  return cv.b;
}

// async global->LDS, 16B per lane; LDS dest is wave-uniform base + lane*16 (m97/m104)
__device__ __forceinline__ void glds16(const void* g, void* l){
  __builtin_amdgcn_global_load_lds(
      (__attribute__((address_space(1))) void*)(void*)g,
      (__attribute__((address_space(3))) void*)l,
      16, 0, 0);
}

// ---------------- prep: weight cvt (blocks 0..4095) + gates/qbf (4096..4351) + tab (4352..4479) ----------------
__global__ __launch_bounds__(256) void prep_kernel(
    const float* __restrict__ q_w, const float* __restrict__ k_w,
    const float* __restrict__ v_w, const float* __restrict__ out_w,
    __bf16* __restrict__ wq, __bf16* __restrict__ wk,
    __bf16* __restrict__ wv, __bf16* __restrict__ wo,
    const float* __restrict__ query, const float* __restrict__ gw,
    const float* __restrict__ gb, const float* __restrict__ ga,
    float* __restrict__ gates, __bf16* __restrict__ qbf,
    const float* __restrict__ rel_bias, __bf16* __restrict__ tab)
{
  const int bid = blockIdx.x;
  const int tid = threadIdx.x;
  if (bid < 4096){
    // ---- weight fp32->bf16: 4 matrices x 1M elems ----
    const float* a; __bf16* o;
    switch (bid >> 10){
      case 0: a = q_w;  o = wq; break;
      case 1: a = k_w;  o = wk; break;
      case 2: a = v_w;  o = wv; break;
      default: a = out_w; o = wo; break;
    }
    int i = ((bid & 1023) * 256 + tid) * 4;
    float4 v = *(const float4*)(a + i);
    bf16x4 r;
    r[0] = f2bf(v.x); r[1] = f2bf(v.y); r[2] = f2bf(v.z); r[3] = f2bf(v.w);
    *(bf16x4*)(o + i) = r;
  } else if (bid < 4352){
    // ---- gates + query bf16: wave = one t-row (64 lanes = 64 bh) ----
    int t = (bid - 4096) * 4 + (tid >> 6);
    int bh = tid & 63;
    int h = bh & 15;
    const float* q = query + (size_t)t * E_ * B_ + bh * 64;
    __bf16* qo = qbf + (size_t)t * E_ * B_ + bh * 64;
    float g[8];
    #pragma unroll
    for (int e = 0; e < 8; e++) g[e] = gb[e];
    #pragma unroll
    for (int c = 0; c < 8; c++){
      float4 v0 = *(const float4*)(q + c * 8);
      float4 v1 = *(const float4*)(q + c * 8 + 4);
      bf16x8 o;
      o[0] = f2bf(v0.x); o[1] = f2bf(v0.y); o[2] = f2bf(v0.z); o[3] = f2bf(v0.w);
      o[4] = f2bf(v1.x); o[5] = f2bf(v1.y); o[6] = f2bf(v1.z); o[7] = f2bf(v1.w);
      *(bf16x8*)(qo + c * 8) = o;
      #pragma unroll
      for (int e = 0; e < 8; e++){
        const float* w = gw + e * 64 + c * 8;     // uniform -> s_load
        g[e] += v0.x * w[0] + v0.y * w[1] + v0.z * w[2] + v0.w * w[3]
              + v1.x * w[4] + v1.y * w[5] + v1.z * w[6] + v1.w * w[7];
      }
    }
    float a0 = (g[0] + g[1]) + (g[2] + g[3]);
    float a1 = (g[4] + g[5]) + (g[6] + g[7]);
    float sa = 1.f / (1.f + __expf(-a0));
    float sb = 1.f / (1.f + __expf(-a1));
    gates[bh * T_ + t] = (sa * (sb * ga[h] - 1.0f) + 2.0f) * LOG2E;   // pre-scaled for exp2
  } else {
    // ---- rel-bias table: tab[h][rp+1023] (bf16) ----
    int tb = bid - 4352;               // 0..127
    int h = tb >> 3;
    int i = (tb & 7) * 256 + tid;
    if (i < 2047){
      int rp = i - 1023;
      int base = rp > 0 ? 16 : 0;
      int arp = rp < 0 ? -rp : rp;
      int off;
      if (arp < 8) off = arp;
      else {
        float val = (logf((float)arp * 0.125f) / 2.772588722239781f) * 8.0f;
        int lg = (int)val;
        off = 8 + (lg > 7 ? 7 : lg);
      }
      tab[h * 2047 + i] = f2bf(rel_bias[(base + off) * H_ + h]);
    }
  }
}

// ---------------- QKV GEMM: 128x128 tile, BK=64, XOR-swizzled LDS, XCD-swizzled grid (768) ----------------
// LDS chunk layout: slot (row, c) holds global 16B-chunk (row, c ^ (row&7)).
// Staging picks swizzled global source (LDS dest is HW-fixed lane*16); frag reads
// address chunk (kq*4+quad)^(l15&7) -> all 8 bank-groups covered, 2-way max (free, m136).
__global__ __launch_bounds__(256) void gemm_qkv(
    const __bf16* __restrict__ A,
    const __bf16* __restrict__ W0, const __bf16* __restrict__ W1, const __bf16* __restrict__ W2,
    const float* __restrict__ b0, const float* __restrict__ b1, const float* __restrict__ b2,
    __bf16* out0, __bf16* out1, __bf16* out2)
{
  __shared__ __bf16 smem[2][128 * 64];   // As/Bs (32 KB); reused for v-transpose epilogue
  __bf16* As = smem[0];
  __bf16* Bs = smem[1];
  const int tid = threadIdx.x;
  const int lane = tid & 63, wid = tid >> 6;
  const int l15 = lane & 15, quad = lane >> 4;
  const int wm = wid >> 1, wn = wid & 1;
  // XCD swizzle: xcd = d&7 owns m-slabs [xcd*4, xcd*4+4); j&3 = m fast, nz slow (W-slab reuse)
  const int dd = blockIdx.x;
  const int j = dd >> 3;
  const int m0 = ((dd & 7) * 4 + (j & 3)) * 128;
  const int nz = j >> 2;                 // 0..23
  const int n0 = (nz & 7) * 128;
  const int z = nz >> 3;

  const __bf16* W = W0;
  const float* bias = b0;
  float scale = 1.0f;
  __bf16* outp = out0;
  if (z == 0){ scale = 0.125f * LOG2E; }               // q: *DH^-0.5 * log2e
  else if (z == 1){ W = W1; bias = b1; outp = out1; }  // k
  else            { W = W2; bias = b2; outp = out2; }  // v

  f32x4 acc[4][4];
  #pragma unroll
  for (int i = 0; i < 4; i++)
    #pragma unroll
    for (int jj = 0; jj < 4; jj++){
      acc[i][jj][0] = 0.f; acc[i][jj][1] = 0.f; acc[i][jj][2] = 0.f; acc[i][jj][3] = 0.f;
    }

  const int grow = lane >> 3;                 // row within 8-row staging group (== row&7)
  const int gcol = (((lane & 7) ^ grow) * 8); // XOR-swizzled source chunk
  const int sw = (l15 & 7);                   // read-side row swizzle key

  for (int k0 = 0; k0 < E_; k0 += 64){
    __syncthreads();
    #pragma unroll
    for (int r = 0; r < 4; r++){
      int rb = wid * 32 + r * 8;        // wave covers rows [wid*32, wid*32+32)
      glds16(A + (size_t)(m0 + rb + grow) * E_ + k0 + gcol, &As[rb * 64]);
      glds16(W + (size_t)(n0 + rb + grow) * E_ + k0 + gcol, &Bs[rb * 64]);
    }
    __syncthreads();
    #pragma unroll
    for (int kq = 0; kq < 2; kq++){
      const int ce = ((kq * 4 + quad) ^ sw) * 8;   // swizzled chunk offset (elems)
      bf16x8 am[4], bn[4];
      #pragma unroll
      for (int i = 0; i < 4; i++) am[i] = *(const bf16x8*)&As[(wm * 64 + i * 16 + l15) * 64 + ce];
      #pragma unroll
      for (int jj = 0; jj < 4; jj++) bn[jj] = *(const bf16x8*)&Bs[(wn * 64 + jj * 16 + l15) * 64 + ce];
      #pragma unroll
      for (int i = 0; i < 4; i++)
        #pragma unroll
        for (int jj = 0; jj < 4; jj++)
          acc[i][jj] = __builtin_amdgcn_mfma_f32_16x16x32_bf16(am[i], bn[jj], acc[i][jj], 0, 0, 0);
    }
  }

  if (z != 2){
    // q/k epilogue: C/D layout col=lane&15, row=quad*4+reg (m89/m91); 32B-granule scatter
    #pragma unroll
    for (int i = 0; i < 4; i++){
      const int row0 = m0 + wm * 64 + i * 16 + quad * 4;
      #pragma unroll
      for (int jj = 0; jj < 4; jj++){
        const int col = n0 + wn * 64 + jj * 16 + l15;
        const float bc = bias[col];
        #pragma unroll
        for (int r = 0; r < 4; r++){
          float v = (acc[i][jj][r] + bc) * scale;
          int row = row0 + r;
          int t = row >> 2, bb = row & 3;       // m = t*B + b
          int hh = col >> 6, d2 = col & 63;     // n = h*DH + d
          outp[(size_t)((bb * H_ + hh) * T_ + t) * DH_ + d2] = f2bf(v);
        }
      }
    }
  } else {
    // v epilogue: transpose via LDS -> (B,H,DH,T); per-thread 64B-contiguous t-runs.
    __bf16 (*vbuf)[4][32] = (__bf16 (*)[4][32])&smem[0][0];   // [n_local(64)][bb(4)][t_local(32)]
    const int tb0 = m0 >> 2;
    #pragma unroll
    for (int p = 0; p < 2; p++){
      __syncthreads();
      if (wn == p){
        #pragma unroll
        for (int i = 0; i < 4; i++){
          const int t_local = wm * 16 + i * 4 + quad;
          #pragma unroll
          for (int jj = 0; jj < 4; jj++){
            const int nl = jj * 16 + l15;
            const float bc = bias[n0 + p * 64 + nl];
            #pragma unroll
            for (int r = 0; r < 4; r++)
              vbuf[nl][r][t_local] = f2bf(acc[i][jj][r] + bc);
          }
        }
      }
      __syncthreads();
      const int nl = tid >> 2;
      const int bb = tid & 3;
      const int colg = n0 + p * 64 + nl;
      const int hh = colg >> 6, d2 = colg & 63;
      __bf16* dst = outp + (size_t)((bb * H_ + hh) * DH_ + d2) * T_ + tb0;
      const __bf16* src = &vbuf[nl][bb][0];
      #pragma unroll
      for (int c = 0; c < 4; c++)
        *(bf16x8*)(dst + c * 8) = *(const bf16x8*)(src + c * 8);
    }
  }
}

// ---------------- out-proj GEMM: 64x128 tile, BK=64, XOR-swizzled LDS, XCD grid (512), fp32 write ----------------
__global__ __launch_bounds__(256) void gemm_out(
    const __bf16* __restrict__ A, const __bf16* __restrict__ W,
    const float* __restrict__ bias, float* __restrict__ out)
{
  __shared__ __bf16 As[64 * 64];    // 8 KB
  __shared__ __bf16 Bs[128 * 64];   // 16 KB
  const int tid = threadIdx.x;
  const int lane = tid & 63, wid = tid >> 6;
  const int l15 = lane & 15, quad = lane >> 4;
  const int wm = wid >> 1, wn = wid & 1;
  const int dd = blockIdx.x;
  const int j = dd >> 3;
  const int m0 = ((dd & 7) * 8 + (j & 7)) * 64;
  const int n0 = (j >> 3) * 128;

  f32x4 acc[2][4];
  #pragma unroll
  for (int i = 0; i < 2; i++)
    #pragma unroll
    for (int jj = 0; jj < 4; jj++){
      acc[i][jj][0] = 0.f; acc[i][jj][1] = 0.f; acc[i][jj][2] = 0.f; acc[i][jj][3] = 0.f;
    }

  const int grow = lane >> 3;
  const int gcol = (((lane & 7) ^ grow) * 8);
  const int sw = (l15 & 7);

  for (int k0 = 0; k0 < E_; k0 += 64){
    __syncthreads();
    #pragma unroll
    for (int r = 0; r < 2; r++){
      int rbA = wid * 16 + r * 8;
      glds16(A + (size_t)(m0 + rbA + grow) * E_ + k0 + gcol, &As[rbA * 64]);
    }
    #pragma unroll
    for (int r = 0; r < 4; r++){
      int rbB = wid * 32 + r * 8;
      glds16(W + (size_t)(n0 + rbB + grow) * E_ + k0 + gcol, &Bs[rbB * 64]);
    }
    __syncthreads();
    #pragma unroll
    for (int kq = 0; kq < 2; kq++){
      const int ce = ((kq * 4 + quad) ^ sw) * 8;
      bf16x8 am[2], bn[4];
      #pragma unroll
      for (int i = 0; i < 2; i++) am[i] = *(const bf16x8*)&As[(wm * 32 + i * 16 + l15) * 64 + ce];
      #pragma unroll
      for (int jj = 0; jj < 4; jj++) bn[jj] = *(const bf16x8*)&Bs[(wn * 64 + jj * 16 + l15) * 64 + ce];
      #pragma unroll
      for (int i = 0; i < 2; i++)
        #pragma unroll
        for (int jj = 0; jj < 4; jj++)
          acc[i][jj] = __builtin_amdgcn_mfma_f32_16x16x32_bf16(am[i], bn[jj], acc[i][jj], 0, 0, 0);
    }
  }

  #pragma unroll
  for (int i = 0; i < 2; i++){
    const int row0 = m0 + wm * 32 + i * 16 + quad * 4;
    #pragma unroll
    for (int jj = 0; jj < 4; jj++){
      const int col = n0 + wn * 64 + jj * 16 + l15;
      const float bc = bias[col];
      #pragma unroll
      for (int r = 0; r < 4; r++)
        out[(size_t)(row0 + r) * E_ + col] = acc[i][jj][r] + bc;
    }
  }
}

// ---------------- flash attention: 128 t per block, 2 t-groups/wave, XCD-swizzled ----------------
__global__ __launch_bounds__(256) void attn_kernel(
    const __bf16* __restrict__ qg, const __bf16* __restrict__ kg, const __bf16* __restrict__ vgT,
    const float* __restrict__ gates, const __bf16* __restrict__ tab,
    __bf16* __restrict__ ctx)
{
  const int LD = 72;                   // 144B rows
  __shared__ __bf16 Ks[64 * LD];       // K-tile (s, d)
  __shared__ __bf16 Vt[64 * LD];       // V^T tile (d, s)
  __shared__ __bf16 Pt[4][2][16 * LD]; // per-wave, per-t-group P^T — wave-local, no barrier
  __shared__ __bf16 tabh[2048];

  const int tid = threadIdx.x;
  const int lane = tid & 63, wid = tid >> 6;
  const int l15 = lane & 15, quad = lane >> 4;
  const int dgrid = blockIdx.x;
  const int jj = dgrid >> 3;
  const int bh = (dgrid & 7) + 8 * (jj & 7);
  const int tq = jj >> 3;              // 0..7 -> t-base tq*128
  const int b = bh >> 4, h = bh & 15;
  const __bf16* qb = qg + (size_t)bh * T_ * DH_;
  const __bf16* kb = kg + (size_t)bh * T_ * DH_;
  const __bf16* vb = vgT + (size_t)bh * DH_ * T_;

  for (int i = tid; i < 2047; i += 256) tabh[i] = tab[h * 2047 + i];

  const int t0w = tq * 128 + wid * 32; // wave owns 32 t = 2 groups of 16
  bf16x8 bq[2][2];
  float g[2];
  int ibase[2];
  #pragma unroll
  for (int tg = 0; tg < 2; tg++){
    int t_lane = t0w + tg * 16 + l15;
    bq[tg][0] = *(const bf16x8*)(qb + (size_t)t_lane * DH_ + quad * 8);
    bq[tg][1] = *(const bf16x8*)(qb + (size_t)t_lane * DH_ + 32 + quad * 8);
    g[tg] = gates[bh * T_ + t_lane];   // already * log2e
    ibase[tg] = 1023 - t_lane;
  }

  const int r0 = tid >> 3;
  const int c0 = (tid & 7) * 8;

  float l_run[2] = {0.f, 0.f};
  f32x4 O[2][4];
  #pragma unroll
  for (int tg = 0; tg < 2; tg++)
    #pragma unroll
    for (int mt = 0; mt < 4; mt++){ O[tg][mt][0]=0.f; O[tg][mt][1]=0.f; O[tg][mt][2]=0.f; O[tg][mt][3]=0.f; }

  bf16x8 kA = *(const bf16x8*)(kb + (size_t)r0 * DH_ + c0);
  bf16x8 kB = *(const bf16x8*)(kb + (size_t)(r0 + 32) * DH_ + c0);
  bf16x8 vA = *(const bf16x8*)(vb + (size_t)r0 * T_ + c0);
  bf16x8 vB = *(const bf16x8*)(vb + (size_t)(r0 + 32) * T_ + c0);

  for (int s0 = 0; s0 < T_; s0 += 64){
    __syncthreads();
    *(bf16x8*)&Ks[r0 * LD + c0] = kA;
    *(bf16x8*)&Ks[(r0 + 32) * LD + c0] = kB;
    *(bf16x8*)&Vt[r0 * LD + c0] = vA;
    *(bf16x8*)&Vt[(r0 + 32) * LD + c0] = vB;
    __syncthreads();

    int sn = (s0 + 64) & (T_ - 1);
    kA = *(const bf16x8*)(kb + (size_t)(sn + r0) * DH_ + c0);
    kB = *(const bf16x8*)(kb + (size_t)(sn + r0 + 32) * DH_ + c0);
    vA = *(const bf16x8*)(vb + (size_t)r0 * T_ + sn + c0);
    vB = *(const bf16x8*)(vb + (size_t)(r0 + 32) * T_ + sn + c0);

    // S^T = K.Q^T: A=K (shared across tg), B=Q^T. D: S^T[s=nt*16+quad*4+r][t=l15]
    f32x4 S[2][4];
    #pragma unroll
    for (int nt = 0; nt < 4; nt++){
      bf16x8 ak0 = *(const bf16x8*)&Ks[(nt * 16 + l15) * LD + quad * 8];
      bf16x8 ak1 = *(const bf16x8*)&Ks[(nt * 16 + l15) * LD + 32 + quad * 8];
      #pragma unroll
      for (int tg = 0; tg < 2; tg++){
        f32x4 a; a[0]=0.f; a[1]=0.f; a[2]=0.f; a[3]=0.f;
        a = __builtin_amdgcn_mfma_f32_16x16x32_bf16(ak0, bq[tg][0], a, 0, 0, 0);
        a = __builtin_amdgcn_mfma_f32_16x16x32_bf16(ak1, bq[tg][1], a, 0, 0, 0);
        S[tg][nt] = a;
      }
    }

    // bias + exp2 (no max-shift: scores O(10), fp32 exp2 safe; softmax shift-invariant)
    #pragma unroll
    for (int tg = 0; tg < 2; tg++){
      const int ib = ibase[tg] + s0;
      #pragma unroll
      for (int nt = 0; nt < 4; nt++)
        #pragma unroll
        for (int r = 0; r < 4; r++)
          S[tg][nt][r] = __builtin_amdgcn_exp2f(S[tg][nt][r] + g[tg] * (float)tabh[ib + nt * 16 + quad * 4 + r]);

      __bf16* pw = &Pt[wid][tg][0];
      #pragma unroll
      for (int nt = 0; nt < 4; nt++){
        bf16x4 p;
        p[0] = f2bf_fast(S[tg][nt][0]); p[1] = f2bf_fast(S[tg][nt][1]);
        p[2] = f2bf_fast(S[tg][nt][2]); p[3] = f2bf_fast(S[tg][nt][3]);
        *(bf16x4*)&pw[l15 * LD + nt * 16 + quad * 4] = p;
      }

      float rs = 0.f;
      #pragma unroll
      for (int nt = 0; nt < 4; nt++) rs += (S[tg][nt][0] + S[tg][nt][1]) + (S[tg][nt][2] + S[tg][nt][3]);
      rs += __shfl_xor(rs, 16, 64);
      rs += __shfl_xor(rs, 32, 64);
      l_run[tg] += rs;
    }

    // O^T += V^T.P^T: A=V^T (shared across tg), B=P^T
    #pragma unroll
    for (int ks = 0; ks < 2; ks++){
      bf16x8 bp[2];
      #pragma unroll
      for (int tg = 0; tg < 2; tg++)
        bp[tg] = *(const bf16x8*)&Pt[wid][tg][l15 * LD + ks * 32 + quad * 8];
      #pragma unroll
      for (int mt = 0; mt < 4; mt++){
        bf16x8 av = *(const bf16x8*)&Vt[(mt * 16 + l15) * LD + ks * 32 + quad * 8];
        #pragma unroll
        for (int tg = 0; tg < 2; tg++)
          O[tg][mt] = __builtin_amdgcn_mfma_f32_16x16x32_bf16(av, bp[tg], O[tg][mt], 0, 0, 0);
      }
    }
  }

  #pragma unroll
  for (int tg = 0; tg < 2; tg++){
    const int t_lane = t0w + tg * 16 + l15;
    const float inv = 1.f / l_run[tg];
    #pragma unroll
    for (int mt = 0; mt < 4; mt++){
      bf16x4 o;
      o[0] = f2bf(O[tg][mt][0] * inv); o[1] = f2bf(O[tg][mt][1] * inv);
      o[2] = f2bf(O[tg][mt][2] * inv); o[3] = f2bf(O[tg][mt][3] * inv);
      *(bf16x4*)&ctx[(size_t)(t_lane * B_ + b) * E_ + h * DH_ + mt * 16 + quad * 4] = o;
    }
  }
}

extern "C" void kernel_launch(void* const* d_in, const int* in_sizes, int n_in,
                              void* d_out, int out_size, void* d_ws, size_t ws_size,
                              hipStream_t stream)
{
  (void)in_sizes; (void)n_in; (void)out_size; (void)ws_size;
  const float* query    = (const float*)d_in[0];
  const float* q_w      = (const float*)d_in[1];
  const float* q_b      = (const float*)d_in[2];
  const float* k_w      = (const float*)d_in[3];
  const float* k_b      = (const float*)d_in[4];
  const float* v_w      = (const float*)d_in[5];
  const float* v_b      = (const float*)d_in[6];
  const float* out_w    = (const float*)d_in[7];
  const float* out_b    = (const float*)d_in[8];
  const float* rel_bias = (const float*)d_in[9];
  const float* grep_w   = (const float*)d_in[10];
  const float* grep_b   = (const float*)d_in[11];
  const float* grep_a   = (const float*)d_in[12];

  char* ws = (char*)d_ws;
  size_t off = 0;
  __bf16* qbf = (__bf16*)(ws + off); off += (size_t)4096 * 1024 * 2;   // query bf16 (TB, E)
  __bf16* wq  = (__bf16*)(ws + off); off += (size_t)1024 * 1024 * 2;
  __bf16* wk  = (__bf16*)(ws + off); off += (size_t)1024 * 1024 * 2;
  __bf16* wv  = (__bf16*)(ws + off); off += (size_t)1024 * 1024 * 2;
  __bf16* wo  = (__bf16*)(ws + off); off += (size_t)1024 * 1024 * 2;
  __bf16* qh  = (__bf16*)(ws + off); off += (size_t)4096 * 1024 * 2;   // (B,H,T,DH)
  __bf16* kh  = (__bf16*)(ws + off); off += (size_t)4096 * 1024 * 2;   // (B,H,T,DH)
  __bf16* vhT = (__bf16*)(ws + off); off += (size_t)4096 * 1024 * 2;   // (B,H,DH,T)
  __bf16* ctx = (__bf16*)(ws + off); off += (size_t)4096 * 1024 * 2;   // (TB, E)
  float* gates = (float*)(ws + off); off += (size_t)65536 * 4;         // (B*H, T), * log2e
  __bf16* tab  = (__bf16*)(ws + off); off += (size_t)16 * 2047 * 2;    // (H, 2047) bf16

  prep_kernel<<<4480, 256, 0, stream>>>(q_w, k_w, v_w, out_w, wq, wk, wv, wo,
                                        query, grep_w, grep_b, grep_a, gates, qbf,
                                        rel_bias, tab);
  gemm_qkv<<<768, 256, 0, stream>>>(qbf, wq, wk, wv, q_b, k_b, v_b, qh, kh, vhT);
  attn_kernel<<<512, 256, 0, stream>>>(qh, kh, vhT, gates, tab, ctx);
  gemm_out<<<512, 256, 0, stream>>>(ctx, wo, out_b, (float*)d_out);
}

// Round 7
// 207.573 us; speedup vs baseline: 1.1313x; 1.0675x over previous
//
#include <hip/hip_runtime.h>
#include <math.h>

// Problem constants (reference: T,B,E,H = 1024,4,1024,16; DH=64; 32 buckets, max_dist 128)
#define T_ 1024
#define B_ 4
#define E_ 1024
#define H_ 16
#define DH_ 64

#define LOG2E 1.44269504088896f

typedef __attribute__((ext_vector_type(8))) __bf16 bf16x8;
typedef __attribute__((ext_vector_type(4))) __bf16 bf16x4;
typedef __attribute__((ext_vector_type(4))) float f32x4;

// fp32 -> bf16 round-to-nearest-even
__device__ __forceinline__ __bf16 f2bf(float x){
  union { unsigned short u; __bf16 b; } cv;
  unsigned u32 = __float_as_uint(x);
  cv.u = (unsigned short)((u32 + 0x7fffu + ((u32 >> 16) & 1u)) >> 16);
  return cv.b;
}
// fp32 -> bf16 round-half-up (cheaper; used only for P >= 0)
__device__ __forceinline__ __bf16 f2bf_fast(float x){
  union { unsigned short u; __bf16 b; } cv;
  cv.u = (unsigned short)((__float_as_uint(x) + 0x8000u) >> 16);
  return cv.b;
}

// async global->LDS, 16B per lane; LDS dest is wave-uniform base + lane*16 (m97/m104)
__device__ __forceinline__ void glds16(const void* g, void* l){
  __builtin_amdgcn_global_load_lds(
      (__attribute__((address_space(1))) void*)(void*)g,
      (__attribute__((address_space(3))) void*)l,
      16, 0, 0);
}

// ---------------- prep: weight cvt (blocks 0..4095) + gates/qbf (4096..4351) + tab (4352..4479) ----------------
__global__ __launch_bounds__(256) void prep_kernel(
    const float* __restrict__ q_w, const float* __restrict__ k_w,
    const float* __restrict__ v_w, const float* __restrict__ out_w,
    __bf16* __restrict__ wq, __bf16* __restrict__ wk,
    __bf16* __restrict__ wv, __bf16* __restrict__ wo,
    const float* __restrict__ query, const float* __restrict__ gw,
    const float* __restrict__ gb, const float* __restrict__ ga,
    float* __restrict__ gates, __bf16* __restrict__ qbf,
    const float* __restrict__ rel_bias, __bf16* __restrict__ tab)
{
  const int bid = blockIdx.x;
  const int tid = threadIdx.x;
  if (bid < 4096){
    const float* a; __bf16* o;
    switch (bid >> 10){
      case 0: a = q_w;  o = wq; break;
      case 1: a = k_w;  o = wk; break;
      case 2: a = v_w;  o = wv; break;
      default: a = out_w; o = wo; break;
    }
    int i = ((bid & 1023) * 256 + tid) * 4;
    float4 v = *(const float4*)(a + i);
    bf16x4 r;
    r[0] = f2bf(v.x); r[1] = f2bf(v.y); r[2] = f2bf(v.z); r[3] = f2bf(v.w);
    *(bf16x4*)(o + i) = r;
  } else if (bid < 4352){
    int t = (bid - 4096) * 4 + (tid >> 6);
    int bh = tid & 63;
    int h = bh & 15;
    const float* q = query + (size_t)t * E_ * B_ + bh * 64;
    __bf16* qo = qbf + (size_t)t * E_ * B_ + bh * 64;
    float g[8];
    #pragma unroll
    for (int e = 0; e < 8; e++) g[e] = gb[e];
    #pragma unroll
    for (int c = 0; c < 8; c++){
      float4 v0 = *(const float4*)(q + c * 8);
      float4 v1 = *(const float4*)(q + c * 8 + 4);
      bf16x8 o;
      o[0] = f2bf(v0.x); o[1] = f2bf(v0.y); o[2] = f2bf(v0.z); o[3] = f2bf(v0.w);
      o[4] = f2bf(v1.x); o[5] = f2bf(v1.y); o[6] = f2bf(v1.z); o[7] = f2bf(v1.w);
      *(bf16x8*)(qo + c * 8) = o;
      #pragma unroll
      for (int e = 0; e < 8; e++){
        const float* w = gw + e * 64 + c * 8;     // uniform -> s_load
        g[e] += v0.x * w[0] + v0.y * w[1] + v0.z * w[2] + v0.w * w[3]
              + v1.x * w[4] + v1.y * w[5] + v1.z * w[6] + v1.w * w[7];
      }
    }
    float a0 = (g[0] + g[1]) + (g[2] + g[3]);
    float a1 = (g[4] + g[5]) + (g[6] + g[7]);
    float sa = 1.f / (1.f + __expf(-a0));
    float sb = 1.f / (1.f + __expf(-a1));
    gates[bh * T_ + t] = (sa * (sb * ga[h] - 1.0f) + 2.0f) * LOG2E;   // pre-scaled for exp2
  } else {
    int tb = bid - 4352;               // 0..127
    int h = tb >> 3;
    int i = (tb & 7) * 256 + tid;
    if (i < 2047){
      int rp = i - 1023;
      int base = rp > 0 ? 16 : 0;
      int arp = rp < 0 ? -rp : rp;
      int off;
      if (arp < 8) off = arp;
      else {
        float val = (logf((float)arp * 0.125f) / 2.772588722239781f) * 8.0f;
        int lg = (int)val;
        off = 8 + (lg > 7 ? 7 : lg);
      }
      tab[h * 2047 + i] = f2bf(rel_bias[(base + off) * H_ + h]);
    }
  }
}

// ---------------- fused QKV GEMM: one block = 128 m-rows x 64 n-cols x {q,k,v} ----------------
// A staged ONCE per K-iter, 3 W-tiles staged alongside: 48 MFMA per wave per barrier-pair
// (vs 32 in the split version) and A-staging amortized 3x. Grid 512 (2 blocks/CU, 40KB LDS).
// XCD swizzle: xcd = d&7 owns m-slabs [xcd*4, xcd*4+4) -> 1MB A-slab L2-resident over 16 n-tiles.
// XOR-swizzled LDS chunk layout (slot c holds chunk c^(row&7)) -> 2-way max bank alias (free).
__global__ __launch_bounds__(256, 2) void gemm_qkv(
    const __bf16* __restrict__ A,
    const __bf16* __restrict__ W0, const __bf16* __restrict__ W1, const __bf16* __restrict__ W2,
    const float* __restrict__ b0, const float* __restrict__ b1, const float* __restrict__ b2,
    __bf16* out0, __bf16* out1, __bf16* out2)
{
  __shared__ __bf16 As[128 * 64];      // 16 KB; reused as v-transpose buffer in epilogue
  __shared__ __bf16 Bs[3][64 * 64];    // 3 x 8 KB
  const int tid = threadIdx.x;
  const int lane = tid & 63, wid = tid >> 6;
  const int l15 = lane & 15, quad = lane >> 4;
  const int dd = blockIdx.x;
  const int j = dd >> 3;
  const int m0 = ((dd & 7) * 4 + (j & 3)) * 128;   // m fast within XCD -> A-slab reuse
  const int nt = j >> 2;                            // 0..15 = head index
  const int n0 = nt * 64;

  f32x4 acc[3][2][4];
  #pragma unroll
  for (int z = 0; z < 3; z++)
    #pragma unroll
    for (int i = 0; i < 2; i++)
      #pragma unroll
      for (int jj = 0; jj < 4; jj++){
        acc[z][i][jj][0] = 0.f; acc[z][i][jj][1] = 0.f;
        acc[z][i][jj][2] = 0.f; acc[z][i][jj][3] = 0.f;
      }

  const int grow = lane >> 3;                 // row within 8-row staging group
  const int gcol = (((lane & 7) ^ grow) * 8); // XOR-swizzled source chunk
  const int sw = (l15 & 7);                   // read-side swizzle key

  for (int k0 = 0; k0 < E_; k0 += 64){
    __syncthreads();
    #pragma unroll
    for (int r = 0; r < 4; r++){
      int rb = wid * 32 + r * 8;              // As rows [wid*32, wid*32+32)
      glds16(A + (size_t)(m0 + rb + grow) * E_ + k0 + gcol, &As[rb * 64]);
    }
    #pragma unroll
    for (int r = 0; r < 2; r++){
      int rb = wid * 16 + r * 8;              // Bs rows [wid*16, wid*16+16)
      glds16(W0 + (size_t)(n0 + rb + grow) * E_ + k0 + gcol, &Bs[0][rb * 64]);
      glds16(W1 + (size_t)(n0 + rb + grow) * E_ + k0 + gcol, &Bs[1][rb * 64]);
      glds16(W2 + (size_t)(n0 + rb + grow) * E_ + k0 + gcol, &Bs[2][rb * 64]);
    }
    __syncthreads();
    #pragma unroll
    for (int kq = 0; kq < 2; kq++){
      const int ce = ((kq * 4 + quad) ^ sw) * 8;
      bf16x8 am[2];
      #pragma unroll
      for (int i = 0; i < 2; i++) am[i] = *(const bf16x8*)&As[(wid * 32 + i * 16 + l15) * 64 + ce];
      #pragma unroll
      for (int z = 0; z < 3; z++){
        bf16x8 bn[4];
        #pragma unroll
        for (int jj = 0; jj < 4; jj++) bn[jj] = *(const bf16x8*)&Bs[z][(jj * 16 + l15) * 64 + ce];
        #pragma unroll
        for (int i = 0; i < 2; i++)
          #pragma unroll
          for (int jj = 0; jj < 4; jj++)
            acc[z][i][jj] = __builtin_amdgcn_mfma_f32_16x16x32_bf16(am[i], bn[jj], acc[z][i][jj], 0, 0, 0);
      }
    }
  }

  // ---- q/k epilogues: C/D layout col=lane&15, row=quad*4+reg (m89/m91); 32B-granule scatter ----
  #pragma unroll
  for (int z = 0; z < 2; z++){
    __bf16* outp = z ? out1 : out0;
    const float* bias = z ? b1 : b0;
    const float scale = z ? 1.0f : 0.125f * LOG2E;   // q: *DH^-0.5 * log2e
    #pragma unroll
    for (int i = 0; i < 2; i++){
      const int row0 = m0 + wid * 32 + i * 16 + quad * 4;
      #pragma unroll
      for (int jj = 0; jj < 4; jj++){
        const int col = n0 + jj * 16 + l15;
        const float bc = bias[col];
        const int d2 = col & 63;
        #pragma unroll
        for (int r = 0; r < 4; r++){
          float v = (acc[z][i][jj][r] + bc) * scale;
          int row = row0 + r;
          int t = row >> 2, bb = row & 3;     // m = t*B + b
          outp[(size_t)((bb * H_ + nt) * T_ + t) * DH_ + d2] = f2bf(v);
        }
      }
    }
  }

  // ---- v epilogue: transpose via LDS -> (B,H,DH,T); 64B-contiguous per-thread t-runs ----
  __syncthreads();                             // K-loop reads of As done; reuse as vbuf
  __bf16 (*vbuf)[4][32] = (__bf16 (*)[4][32])&As[0];   // [nl(64)][bb(4)][t_local(32)]
  #pragma unroll
  for (int i = 0; i < 2; i++){
    const int t_local = wid * 8 + i * 4 + quad;        // (local row)>>2 ; bb == r
    #pragma unroll
    for (int jj = 0; jj < 4; jj++){
      const int nl = jj * 16 + l15;
      const float bc = b2[n0 + nl];
      #pragma unroll
      for (int r = 0; r < 4; r++)
        vbuf[nl][r][t_local] = f2bf(acc[2][i][jj][r] + bc);
    }
  }
  __syncthreads();
  {
    const int nl = tid >> 2;                   // 0..63 (= d within head)
    const int bb = tid & 3;
    __bf16* dst = out2 + (size_t)((bb * H_ + nt) * DH_ + nl) * T_ + (m0 >> 2);
    const __bf16* src = &vbuf[nl][bb][0];
    #pragma unroll
    for (int c = 0; c < 4; c++)
      *(bf16x8*)(dst + c * 8) = *(const bf16x8*)(src + c * 8);
  }
}

// ---------------- out-proj GEMM: 64x128 tile, BK=64, XOR-swizzled LDS, XCD grid (512), fp32 write ----------------
__global__ __launch_bounds__(256) void gemm_out(
    const __bf16* __restrict__ A, const __bf16* __restrict__ W,
    const float* __restrict__ bias, float* __restrict__ out)
{
  __shared__ __bf16 As[64 * 64];    // 8 KB
  __shared__ __bf16 Bs[128 * 64];   // 16 KB
  const int tid = threadIdx.x;
  const int lane = tid & 63, wid = tid >> 6;
  const int l15 = lane & 15, quad = lane >> 4;
  const int wm = wid >> 1, wn = wid & 1;
  const int dd = blockIdx.x;
  const int j = dd >> 3;
  const int m0 = ((dd & 7) * 8 + (j & 7)) * 64;
  const int n0 = (j >> 3) * 128;

  f32x4 acc[2][4];
  #pragma unroll
  for (int i = 0; i < 2; i++)
    #pragma unroll
    for (int jj = 0; jj < 4; jj++){
      acc[i][jj][0] = 0.f; acc[i][jj][1] = 0.f; acc[i][jj][2] = 0.f; acc[i][jj][3] = 0.f;
    }

  const int grow = lane >> 3;
  const int gcol = (((lane & 7) ^ grow) * 8);
  const int sw = (l15 & 7);

  for (int k0 = 0; k0 < E_; k0 += 64){
    __syncthreads();
    #pragma unroll
    for (int r = 0; r < 2; r++){
      int rbA = wid * 16 + r * 8;
      glds16(A + (size_t)(m0 + rbA + grow) * E_ + k0 + gcol, &As[rbA * 64]);
    }
    #pragma unroll
    for (int r = 0; r < 4; r++){
      int rbB = wid * 32 + r * 8;
      glds16(W + (size_t)(n0 + rbB + grow) * E_ + k0 + gcol, &Bs[rbB * 64]);
    }
    __syncthreads();
    #pragma unroll
    for (int kq = 0; kq < 2; kq++){
      const int ce = ((kq * 4 + quad) ^ sw) * 8;
      bf16x8 am[2], bn[4];
      #pragma unroll
      for (int i = 0; i < 2; i++) am[i] = *(const bf16x8*)&As[(wm * 32 + i * 16 + l15) * 64 + ce];
      #pragma unroll
      for (int jj = 0; jj < 4; jj++) bn[jj] = *(const bf16x8*)&Bs[(wn * 64 + jj * 16 + l15) * 64 + ce];
      #pragma unroll
      for (int i = 0; i < 2; i++)
        #pragma unroll
        for (int jj = 0; jj < 4; jj++)
          acc[i][jj] = __builtin_amdgcn_mfma_f32_16x16x32_bf16(am[i], bn[jj], acc[i][jj], 0, 0, 0);
    }
  }

  #pragma unroll
  for (int i = 0; i < 2; i++){
    const int row0 = m0 + wm * 32 + i * 16 + quad * 4;
    #pragma unroll
    for (int jj = 0; jj < 4; jj++){
      const int col = n0 + wn * 64 + jj * 16 + l15;
      const float bc = bias[col];
      #pragma unroll
      for (int r = 0; r < 4; r++)
        out[(size_t)(row0 + r) * E_ + col] = acc[i][jj][r] + bc;
    }
  }
}

// ---------------- flash attention: 128 t per block, 2 t-groups/wave, XCD-swizzled ----------------
__global__ __launch_bounds__(256) void attn_kernel(
    const __bf16* __restrict__ qg, const __bf16* __restrict__ kg, const __bf16* __restrict__ vgT,
    const float* __restrict__ gates, const __bf16* __restrict__ tab,
    __bf16* __restrict__ ctx)
{
  const int LD = 72;                   // 144B rows
  __shared__ __bf16 Ks[64 * LD];       // K-tile (s, d)
  __shared__ __bf16 Vt[64 * LD];       // V^T tile (d, s)
  __shared__ __bf16 Pt[4][2][16 * LD]; // per-wave, per-t-group P^T — wave-local, no barrier
  __shared__ __bf16 tabh[2048];

  const int tid = threadIdx.x;
  const int lane = tid & 63, wid = tid >> 6;
  const int l15 = lane & 15, quad = lane >> 4;
  const int dgrid = blockIdx.x;
  const int jj = dgrid >> 3;
  const int bh = (dgrid & 7) + 8 * (jj & 7);
  const int tq = jj >> 3;              // 0..7 -> t-base tq*128
  const int b = bh >> 4, h = bh & 15;
  const __bf16* qb = qg + (size_t)bh * T_ * DH_;
  const __bf16* kb = kg + (size_t)bh * T_ * DH_;
  const __bf16* vb = vgT + (size_t)bh * DH_ * T_;

  for (int i = tid; i < 2047; i += 256) tabh[i] = tab[h * 2047 + i];

  const int t0w = tq * 128 + wid * 32; // wave owns 32 t = 2 groups of 16
  bf16x8 bq[2][2];
  float g[2];
  int ibase[2];
  #pragma unroll
  for (int tg = 0; tg < 2; tg++){
    int t_lane = t0w + tg * 16 + l15;
    bq[tg][0] = *(const bf16x8*)(qb + (size_t)t_lane * DH_ + quad * 8);
    bq[tg][1] = *(const bf16x8*)(qb + (size_t)t_lane * DH_ + 32 + quad * 8);
    g[tg] = gates[bh * T_ + t_lane];   // already * log2e
    ibase[tg] = 1023 - t_lane;
  }

  const int r0 = tid >> 3;
  const int c0 = (tid & 7) * 8;

  float l_run[2] = {0.f, 0.f};
  f32x4 O[2][4];
  #pragma unroll
  for (int tg = 0; tg < 2; tg++)
    #pragma unroll
    for (int mt = 0; mt < 4; mt++){ O[tg][mt][0]=0.f; O[tg][mt][1]=0.f; O[tg][mt][2]=0.f; O[tg][mt][3]=0.f; }

  bf16x8 kA = *(const bf16x8*)(kb + (size_t)r0 * DH_ + c0);
  bf16x8 kB = *(const bf16x8*)(kb + (size_t)(r0 + 32) * DH_ + c0);
  bf16x8 vA = *(const bf16x8*)(vb + (size_t)r0 * T_ + c0);
  bf16x8 vB = *(const bf16x8*)(vb + (size_t)(r0 + 32) * T_ + c0);

  for (int s0 = 0; s0 < T_; s0 += 64){
    __syncthreads();
    *(bf16x8*)&Ks[r0 * LD + c0] = kA;
    *(bf16x8*)&Ks[(r0 + 32) * LD + c0] = kB;
    *(bf16x8*)&Vt[r0 * LD + c0] = vA;
    *(bf16x8*)&Vt[(r0 + 32) * LD + c0] = vB;
    __syncthreads();

    int sn = (s0 + 64) & (T_ - 1);
    kA = *(const bf16x8*)(kb + (size_t)(sn + r0) * DH_ + c0);
    kB = *(const bf16x8*)(kb + (size_t)(sn + r0 + 32) * DH_ + c0);
    vA = *(const bf16x8*)(vb + (size_t)r0 * T_ + sn + c0);
    vB = *(const bf16x8*)(vb + (size_t)(r0 + 32) * T_ + sn + c0);

    // S^T = K.Q^T: A=K (shared across tg), B=Q^T. D: S^T[s=nt*16+quad*4+r][t=l15]
    f32x4 S[2][4];
    #pragma unroll
    for (int nt = 0; nt < 4; nt++){
      bf16x8 ak0 = *(const bf16x8*)&Ks[(nt * 16 + l15) * LD + quad * 8];
      bf16x8 ak1 = *(const bf16x8*)&Ks[(nt * 16 + l15) * LD + 32 + quad * 8];
      #pragma unroll
      for (int tg = 0; tg < 2; tg++){
        f32x4 a; a[0]=0.f; a[1]=0.f; a[2]=0.f; a[3]=0.f;
        a = __builtin_amdgcn_mfma_f32_16x16x32_bf16(ak0, bq[tg][0], a, 0, 0, 0);
        a = __builtin_amdgcn_mfma_f32_16x16x32_bf16(ak1, bq[tg][1], a, 0, 0, 0);
        S[tg][nt] = a;
      }
    }

    // bias + exp2 (no max-shift: scores O(10), fp32 exp2 safe; softmax shift-invariant)
    #pragma unroll
    for (int tg = 0; tg < 2; tg++){
      const int ib = ibase[tg] + s0;
      #pragma unroll
      for (int nt = 0; nt < 4; nt++)
        #pragma unroll
        for (int r = 0; r < 4; r++)
          S[tg][nt][r] = __builtin_amdgcn_exp2f(S[tg][nt][r] + g[tg] * (float)tabh[ib + nt * 16 + quad * 4 + r]);

      __bf16* pw = &Pt[wid][tg][0];
      #pragma unroll
      for (int nt = 0; nt < 4; nt++){
        bf16x4 p;
        p[0] = f2bf_fast(S[tg][nt][0]); p[1] = f2bf_fast(S[tg][nt][1]);
        p[2] = f2bf_fast(S[tg][nt][2]); p[3] = f2bf_fast(S[tg][nt][3]);
        *(bf16x4*)&pw[l15 * LD + nt * 16 + quad * 4] = p;
      }

      float rs = 0.f;
      #pragma unroll
      for (int nt = 0; nt < 4; nt++) rs += (S[tg][nt][0] + S[tg][nt][1]) + (S[tg][nt][2] + S[tg][nt][3]);
      rs += __shfl_xor(rs, 16, 64);
      rs += __shfl_xor(rs, 32, 64);
      l_run[tg] += rs;
    }

    // O^T += V^T.P^T: A=V^T (shared across tg), B=P^T
    #pragma unroll
    for (int ks = 0; ks < 2; ks++){
      bf16x8 bp[2];
      #pragma unroll
      for (int tg = 0; tg < 2; tg++)
        bp[tg] = *(const bf16x8*)&Pt[wid][tg][l15 * LD + ks * 32 + quad * 8];
      #pragma unroll
      for (int mt = 0; mt < 4; mt++){
        bf16x8 av = *(const bf16x8*)&Vt[(mt * 16 + l15) * LD + ks * 32 + quad * 8];
        #pragma unroll
        for (int tg = 0; tg < 2; tg++)
          O[tg][mt] = __builtin_amdgcn_mfma_f32_16x16x32_bf16(av, bp[tg], O[tg][mt], 0, 0, 0);
      }
    }
  }

  #pragma unroll
  for (int tg = 0; tg < 2; tg++){
    const int t_lane = t0w + tg * 16 + l15;
    const float inv = 1.f / l_run[tg];
    #pragma unroll
    for (int mt = 0; mt < 4; mt++){
      bf16x4 o;
      o[0] = f2bf(O[tg][mt][0] * inv); o[1] = f2bf(O[tg][mt][1] * inv);
      o[2] = f2bf(O[tg][mt][2] * inv); o[3] = f2bf(O[tg][mt][3] * inv);
      *(bf16x4*)&ctx[(size_t)(t_lane * B_ + b) * E_ + h * DH_ + mt * 16 + quad * 4] = o;
    }
  }
}

extern "C" void kernel_launch(void* const* d_in, const int* in_sizes, int n_in,
                              void* d_out, int out_size, void* d_ws, size_t ws_size,
                              hipStream_t stream)
{
  (void)in_sizes; (void)n_in; (void)out_size; (void)ws_size;
  const float* query    = (const float*)d_in[0];
  const float* q_w      = (const float*)d_in[1];
  const float* q_b      = (const float*)d_in[2];
  const float* k_w      = (const float*)d_in[3];
  const float* k_b      = (const float*)d_in[4];
  const float* v_w      = (const float*)d_in[5];
  const float* v_b      = (const float*)d_in[6];
  const float* out_w    = (const float*)d_in[7];
  const float* out_b    = (const float*)d_in[8];
  const float* rel_bias = (const float*)d_in[9];
  const float* grep_w   = (const float*)d_in[10];
  const float* grep_b   = (const float*)d_in[11];
  const float* grep_a   = (const float*)d_in[12];

  char* ws = (char*)d_ws;
  size_t off = 0;
  __bf16* qbf = (__bf16*)(ws + off); off += (size_t)4096 * 1024 * 2;   // query bf16 (TB, E)
  __bf16* wq  = (__bf16*)(ws + off); off += (size_t)1024 * 1024 * 2;
  __bf16* wk  = (__bf16*)(ws + off); off += (size_t)1024 * 1024 * 2;
  __bf16* wv  = (__bf16*)(ws + off); off += (size_t)1024 * 1024 * 2;
  __bf16* wo  = (__bf16*)(ws + off); off += (size_t)1024 * 1024 * 2;
  __bf16* qh  = (__bf16*)(ws + off); off += (size_t)4096 * 1024 * 2;   // (B,H,T,DH)
  __bf16* kh  = (__bf16*)(ws + off); off += (size_t)4096 * 1024 * 2;   // (B,H,T,DH)
  __bf16* vhT = (__bf16*)(ws + off); off += (size_t)4096 * 1024 * 2;   // (B,H,DH,T)
  __bf16* ctx = (__bf16*)(ws + off); off += (size_t)4096 * 1024 * 2;   // (TB, E)
  float* gates = (float*)(ws + off); off += (size_t)65536 * 4;         // (B*H, T), * log2e
  __bf16* tab  = (__bf16*)(ws + off); off += (size_t)16 * 2047 * 2;    // (H, 2047) bf16

  prep_kernel<<<4480, 256, 0, stream>>>(q_w, k_w, v_w, out_w, wq, wk, wv, wo,
                                        query, grep_w, grep_b, grep_a, gates, qbf,
                                        rel_bias, tab);
  gemm_qkv<<<512, 256, 0, stream>>>(qbf, wq, wk, wv, q_b, k_b, v_b, qh, kh, vhT);
  attn_kernel<<<512, 256, 0, stream>>>(qh, kh, vhT, gates, tab, ctx);
  gemm_out<<<512, 256, 0, stream>>>(ctx, wo, out_b, (float*)d_out);
}

// Round 8
// 198.915 us; speedup vs baseline: 1.1806x; 1.0435x over previous
//
#include <hip/hip_runtime.h>
#include <math.h>

// Problem constants (reference: T,B,E,H = 1024,4,1024,16; DH=64; 32 buckets, max_dist 128)
#define T_ 1024
#define B_ 4
#define E_ 1024
#define H_ 16
#define DH_ 64

#define LOG2E 1.44269504088896f

typedef __attribute__((ext_vector_type(8))) __bf16 bf16x8;
typedef __attribute__((ext_vector_type(4))) __bf16 bf16x4;
typedef __attribute__((ext_vector_type(4))) float f32x4;

// fp32 -> bf16 round-to-nearest-even
__device__ __forceinline__ __bf16 f2bf(float x){
  union { unsigned short u; __bf16 b; } cv;
  unsigned u32 = __float_as_uint(x);
  cv.u = (unsigned short)((u32 + 0x7fffu + ((u32 >> 16) & 1u)) >> 16);
  return cv.b;
}
// fp32 -> bf16 round-half-up (cheaper; used only for P >= 0)
__device__ __forceinline__ __bf16 f2bf_fast(float x){
  union { unsigned short u; __bf16 b; } cv;
  cv.u = (unsigned short)((__float_as_uint(x) + 0x8000u) >> 16);
  return cv.b;
}

// async global->LDS, 16B per lane; LDS dest is wave-uniform base + lane*16 (m97/m104)
__device__ __forceinline__ void glds16(const void* g, void* l){
  __builtin_amdgcn_global_load_lds(
      (__attribute__((address_space(1))) void*)(void*)g,
      (__attribute__((address_space(3))) void*)l,
      16, 0, 0);
}

// ---------------- prep: weight cvt (blocks 0..4095) + gates/qbf (4096..4351) + tab (4352..4479) ----------------
__global__ __launch_bounds__(256) void prep_kernel(
    const float* __restrict__ q_w, const float* __restrict__ k_w,
    const float* __restrict__ v_w, const float* __restrict__ out_w,
    __bf16* __restrict__ wq, __bf16* __restrict__ wk,
    __bf16* __restrict__ wv, __bf16* __restrict__ wo,
    const float* __restrict__ query, const float* __restrict__ gw,
    const float* __restrict__ gb, const float* __restrict__ ga,
    float* __restrict__ gates, __bf16* __restrict__ qbf,
    const float* __restrict__ rel_bias, float* __restrict__ tab)
{
  const int bid = blockIdx.x;
  const int tid = threadIdx.x;
  if (bid < 4096){
    const float* a; __bf16* o;
    switch (bid >> 10){
      case 0: a = q_w;  o = wq; break;
      case 1: a = k_w;  o = wk; break;
      case 2: a = v_w;  o = wv; break;
      default: a = out_w; o = wo; break;
    }
    int i = ((bid & 1023) * 256 + tid) * 4;
    float4 v = *(const float4*)(a + i);
    bf16x4 r;
    r[0] = f2bf(v.x); r[1] = f2bf(v.y); r[2] = f2bf(v.z); r[3] = f2bf(v.w);
    *(bf16x4*)(o + i) = r;
  } else if (bid < 4352){
    int t = (bid - 4096) * 4 + (tid >> 6);
    int bh = tid & 63;
    int h = bh & 15;
    const float* q = query + (size_t)t * E_ * B_ + bh * 64;
    __bf16* qo = qbf + (size_t)t * E_ * B_ + bh * 64;
    float g[8];
    #pragma unroll
    for (int e = 0; e < 8; e++) g[e] = gb[e];
    #pragma unroll
    for (int c = 0; c < 8; c++){
      float4 v0 = *(const float4*)(q + c * 8);
      float4 v1 = *(const float4*)(q + c * 8 + 4);
      bf16x8 o;
      o[0] = f2bf(v0.x); o[1] = f2bf(v0.y); o[2] = f2bf(v0.z); o[3] = f2bf(v0.w);
      o[4] = f2bf(v1.x); o[5] = f2bf(v1.y); o[6] = f2bf(v1.z); o[7] = f2bf(v1.w);
      *(bf16x8*)(qo + c * 8) = o;
      #pragma unroll
      for (int e = 0; e < 8; e++){
        const float* w = gw + e * 64 + c * 8;     // uniform -> s_load
        g[e] += v0.x * w[0] + v0.y * w[1] + v0.z * w[2] + v0.w * w[3]
              + v1.x * w[4] + v1.y * w[5] + v1.z * w[6] + v1.w * w[7];
      }
    }
    float a0 = (g[0] + g[1]) + (g[2] + g[3]);
    float a1 = (g[4] + g[5]) + (g[6] + g[7]);
    float sa = 1.f / (1.f + __expf(-a0));
    float sb = 1.f / (1.f + __expf(-a1));
    gates[bh * T_ + t] = (sa * (sb * ga[h] - 1.0f) + 2.0f) * LOG2E;   // pre-scaled for exp2
  } else {
    int tb = bid - 4352;               // 0..127
    int h = tb >> 3;
    int i = (tb & 7) * 256 + tid;
    if (i < 2047){
      int rp = i - 1023;
      int base = rp > 0 ? 16 : 0;
      int arp = rp < 0 ? -rp : rp;
      int off;
      if (arp < 8) off = arp;
      else {
        float val = (logf((float)arp * 0.125f) / 2.772588722239781f) * 8.0f;
        int lg = (int)val;
        off = 8 + (lg > 7 ? 7 : lg);
      }
      tab[h * 2047 + i] = rel_bias[(base + off) * H_ + h];   // fp32 now
    }
  }
}

// ---------------- fused QKV GEMM: one block = 128 m-rows x 64 n-cols x {q,k,v} ----------------
__global__ __launch_bounds__(256, 2) void gemm_qkv(
    const __bf16* __restrict__ A,
    const __bf16* __restrict__ W0, const __bf16* __restrict__ W1, const __bf16* __restrict__ W2,
    const float* __restrict__ b0, const float* __restrict__ b1, const float* __restrict__ b2,
    __bf16* out0, __bf16* out1, __bf16* out2)
{
  __shared__ __bf16 As[128 * 64];      // 16 KB; reused as v-transpose buffer in epilogue
  __shared__ __bf16 Bs[3][64 * 64];    // 3 x 8 KB
  const int tid = threadIdx.x;
  const int lane = tid & 63, wid = tid >> 6;
  const int l15 = lane & 15, quad = lane >> 4;
  const int dd = blockIdx.x;
  const int j = dd >> 3;
  const int m0 = ((dd & 7) * 4 + (j & 3)) * 128;   // m fast within XCD -> A-slab reuse
  const int nt = j >> 2;                            // 0..15 = head index
  const int n0 = nt * 64;

  f32x4 acc[3][2][4];
  #pragma unroll
  for (int z = 0; z < 3; z++)
    #pragma unroll
    for (int i = 0; i < 2; i++)
      #pragma unroll
      for (int jj = 0; jj < 4; jj++){
        acc[z][i][jj][0] = 0.f; acc[z][i][jj][1] = 0.f;
        acc[z][i][jj][2] = 0.f; acc[z][i][jj][3] = 0.f;
      }

  const int grow = lane >> 3;
  const int gcol = (((lane & 7) ^ grow) * 8);
  const int sw = (l15 & 7);

  for (int k0 = 0; k0 < E_; k0 += 64){
    __syncthreads();
    #pragma unroll
    for (int r = 0; r < 4; r++){
      int rb = wid * 32 + r * 8;
      glds16(A + (size_t)(m0 + rb + grow) * E_ + k0 + gcol, &As[rb * 64]);
    }
    #pragma unroll
    for (int r = 0; r < 2; r++){
      int rb = wid * 16 + r * 8;
      glds16(W0 + (size_t)(n0 + rb + grow) * E_ + k0 + gcol, &Bs[0][rb * 64]);
      glds16(W1 + (size_t)(n0 + rb + grow) * E_ + k0 + gcol, &Bs[1][rb * 64]);
      glds16(W2 + (size_t)(n0 + rb + grow) * E_ + k0 + gcol, &Bs[2][rb * 64]);
    }
    __syncthreads();
    #pragma unroll
    for (int kq = 0; kq < 2; kq++){
      const int ce = ((kq * 4 + quad) ^ sw) * 8;
      bf16x8 am[2];
      #pragma unroll
      for (int i = 0; i < 2; i++) am[i] = *(const bf16x8*)&As[(wid * 32 + i * 16 + l15) * 64 + ce];
      #pragma unroll
      for (int z = 0; z < 3; z++){
        bf16x8 bn[4];
        #pragma unroll
        for (int jj = 0; jj < 4; jj++) bn[jj] = *(const bf16x8*)&Bs[z][(jj * 16 + l15) * 64 + ce];
        #pragma unroll
        for (int i = 0; i < 2; i++)
          #pragma unroll
          for (int jj = 0; jj < 4; jj++)
            acc[z][i][jj] = __builtin_amdgcn_mfma_f32_16x16x32_bf16(am[i], bn[jj], acc[z][i][jj], 0, 0, 0);
      }
    }
  }

  #pragma unroll
  for (int z = 0; z < 2; z++){
    __bf16* outp = z ? out1 : out0;
    const float* bias = z ? b1 : b0;
    const float scale = z ? 1.0f : 0.125f * LOG2E;
    #pragma unroll
    for (int i = 0; i < 2; i++){
      const int row0 = m0 + wid * 32 + i * 16 + quad * 4;
      #pragma unroll
      for (int jj = 0; jj < 4; jj++){
        const int col = n0 + jj * 16 + l15;
        const float bc = bias[col];
        const int d2 = col & 63;
        #pragma unroll
        for (int r = 0; r < 4; r++){
          float v = (acc[z][i][jj][r] + bc) * scale;
          int row = row0 + r;
          int t = row >> 2, bb = row & 3;
          outp[(size_t)((bb * H_ + nt) * T_ + t) * DH_ + d2] = f2bf(v);
        }
      }
    }
  }

  __syncthreads();
  __bf16 (*vbuf)[4][32] = (__bf16 (*)[4][32])&As[0];
  #pragma unroll
  for (int i = 0; i < 2; i++){
    const int t_local = wid * 8 + i * 4 + quad;
    #pragma unroll
    for (int jj = 0; jj < 4; jj++){
      const int nl = jj * 16 + l15;
      const float bc = b2[n0 + nl];
      #pragma unroll
      for (int r = 0; r < 4; r++)
        vbuf[nl][r][t_local] = f2bf(acc[2][i][jj][r] + bc);
    }
  }
  __syncthreads();
  {
    const int nl = tid >> 2;
    const int bb = tid & 3;
    __bf16* dst = out2 + (size_t)((bb * H_ + nt) * DH_ + nl) * T_ + (m0 >> 2);
    const __bf16* src = &vbuf[nl][bb][0];
    #pragma unroll
    for (int c = 0; c < 4; c++)
      *(bf16x8*)(dst + c * 8) = *(const bf16x8*)(src + c * 8);
  }
}

// ---------------- out-proj GEMM: 64x128 tile, BK=64, XOR-swizzled LDS, XCD grid (512), fp32 write ----------------
__global__ __launch_bounds__(256) void gemm_out(
    const __bf16* __restrict__ A, const __bf16* __restrict__ W,
    const float* __restrict__ bias, float* __restrict__ out)
{
  __shared__ __bf16 As[64 * 64];
  __shared__ __bf16 Bs[128 * 64];
  const int tid = threadIdx.x;
  const int lane = tid & 63, wid = tid >> 6;
  const int l15 = lane & 15, quad = lane >> 4;
  const int wm = wid >> 1, wn = wid & 1;
  const int dd = blockIdx.x;
  const int j = dd >> 3;
  const int m0 = ((dd & 7) * 8 + (j & 7)) * 64;
  const int n0 = (j >> 3) * 128;

  f32x4 acc[2][4];
  #pragma unroll
  for (int i = 0; i < 2; i++)
    #pragma unroll
    for (int jj = 0; jj < 4; jj++){
      acc[i][jj][0] = 0.f; acc[i][jj][1] = 0.f; acc[i][jj][2] = 0.f; acc[i][jj][3] = 0.f;
    }

  const int grow = lane >> 3;
  const int gcol = (((lane & 7) ^ grow) * 8);
  const int sw = (l15 & 7);

  for (int k0 = 0; k0 < E_; k0 += 64){
    __syncthreads();
    #pragma unroll
    for (int r = 0; r < 2; r++){
      int rbA = wid * 16 + r * 8;
      glds16(A + (size_t)(m0 + rbA + grow) * E_ + k0 + gcol, &As[rbA * 64]);
    }
    #pragma unroll
    for (int r = 0; r < 4; r++){
      int rbB = wid * 32 + r * 8;
      glds16(W + (size_t)(n0 + rbB + grow) * E_ + k0 + gcol, &Bs[rbB * 64]);
    }
    __syncthreads();
    #pragma unroll
    for (int kq = 0; kq < 2; kq++){
      const int ce = ((kq * 4 + quad) ^ sw) * 8;
      bf16x8 am[2], bn[4];
      #pragma unroll
      for (int i = 0; i < 2; i++) am[i] = *(const bf16x8*)&As[(wm * 32 + i * 16 + l15) * 64 + ce];
      #pragma unroll
      for (int jj = 0; jj < 4; jj++) bn[jj] = *(const bf16x8*)&Bs[(wn * 64 + jj * 16 + l15) * 64 + ce];
      #pragma unroll
      for (int i = 0; i < 2; i++)
        #pragma unroll
        for (int jj = 0; jj < 4; jj++)
          acc[i][jj] = __builtin_amdgcn_mfma_f32_16x16x32_bf16(am[i], bn[jj], acc[i][jj], 0, 0, 0);
    }
  }

  #pragma unroll
  for (int i = 0; i < 2; i++){
    const int row0 = m0 + wm * 32 + i * 16 + quad * 4;
    #pragma unroll
    for (int jj = 0; jj < 4; jj++){
      const int col = n0 + wn * 64 + jj * 16 + l15;
      const float bc = bias[col];
      #pragma unroll
      for (int r = 0; r < 4; r++)
        out[(size_t)(row0 + r) * E_ + col] = acc[i][jj][r] + bc;
    }
  }
}

// ---------------- flash attention v5: 64 t per block, 128 thr (2 waves), 4 blocks/CU ----------------
// DMA staging (glds16) with XOR-swizzled 64-elem rows; bucket-saturation: tiles with |s-t|>=128
// use a constant bias (exact T5 bucket clamp) -> no tab reads on ~10/16 iters.
__global__ __launch_bounds__(128) void attn_kernel(
    const __bf16* __restrict__ qg, const __bf16* __restrict__ kg, const __bf16* __restrict__ vgT,
    const float* __restrict__ gates, const float* __restrict__ tab,
    __bf16* __restrict__ ctx)
{
  const int LDP = 72;                  // P rows padded (written by VALU, b64/b128 path)
  __shared__ __bf16 Ks[64 * 64];       // 8 KB, swizzled chunks: slot c holds global chunk c^(row&7)
  __shared__ __bf16 Vt[64 * 64];       // 8 KB, swizzled (rows = d, cols = s)
  __shared__ __bf16 Pt[2][2][16 * LDP];// per-(wave, tg) P^T
  __shared__ float tabh[2048];         // fp32 rel-bias row for this h

  const int tid = threadIdx.x;
  const int lane = tid & 63, wid = tid >> 6;       // 2 waves
  const int l15 = lane & 15, quad = lane >> 4;
  // XCD swizzle: all 16 t-blocks of a bh share XCD slot d&7
  const int dgrid = blockIdx.x;
  const int j = dgrid >> 3;
  const int bh = (dgrid & 7) + 8 * (j & 7);
  const int tq = j >> 3;               // 0..15 -> t-base tq*64
  const int b = bh >> 4, h = bh & 15;
  const __bf16* qb = qg + (size_t)bh * T_ * DH_;
  const __bf16* kb = kg + (size_t)bh * T_ * DH_;
  const __bf16* vb = vgT + (size_t)bh * DH_ * T_;

  for (int i = tid; i < 2047; i += 128) tabh[i] = tab[h * 2047 + i];

  const int t0w = tq * 64 + wid * 32;  // wave owns 32 t = 2 groups of 16
  bf16x8 bq[2][2];
  float g[2];
  int ibase[2];
  #pragma unroll
  for (int tg = 0; tg < 2; tg++){
    int t_lane = t0w + tg * 16 + l15;
    bq[tg][0] = *(const bf16x8*)(qb + (size_t)t_lane * DH_ + quad * 8);
    bq[tg][1] = *(const bf16x8*)(qb + (size_t)t_lane * DH_ + 32 + quad * 8);
    g[tg] = gates[bh * T_ + t_lane];   // already * log2e
    ibase[tg] = 1023 - t_lane;
  }

  const int grow = lane >> 3;                  // staging row within 8-row group
  const int gcol = (((lane & 7) ^ grow) * 8);  // XOR-swizzled source chunk
  const int swf = (l15 & 7);                   // frag-read swizzle key

  float l_run[2] = {0.f, 0.f};
  f32x4 O[2][4];
  #pragma unroll
  for (int tg = 0; tg < 2; tg++)
    #pragma unroll
    for (int mt = 0; mt < 4; mt++){ O[tg][mt][0]=0.f; O[tg][mt][1]=0.f; O[tg][mt][2]=0.f; O[tg][mt][3]=0.f; }

  for (int s0 = 0; s0 < T_; s0 += 64){
    __syncthreads();                   // prev-iter LDS reads done
    #pragma unroll
    for (int r = 0; r < 4; r++){
      int rb = wid * 32 + r * 8;       // wave stages rows [wid*32, wid*32+32)
      glds16(kb + (size_t)(s0 + rb + grow) * DH_ + gcol, &Ks[rb * 64]);
      glds16(vb + (size_t)(rb + grow) * T_ + s0 + gcol, &Vt[rb * 64]);
    }
    __syncthreads();                   // drain DMA -> staged data visible

    // S^T = K.Q^T: A=K (shared across tg), B=Q^T. D: S^T[s=nt*16+quad*4+r][t=l15]
    f32x4 S[2][4];
    #pragma unroll
    for (int nt = 0; nt < 4; nt++){
      const int rowb = (nt * 16 + l15) * 64;
      bf16x8 ak0 = *(const bf16x8*)&Ks[rowb + ((quad ^ swf) * 8)];
      bf16x8 ak1 = *(const bf16x8*)&Ks[rowb + (((4 + quad) ^ swf) * 8)];
      #pragma unroll
      for (int tg = 0; tg < 2; tg++){
        f32x4 a; a[0]=0.f; a[1]=0.f; a[2]=0.f; a[3]=0.f;
        a = __builtin_amdgcn_mfma_f32_16x16x32_bf16(ak0, bq[tg][0], a, 0, 0, 0);
        a = __builtin_amdgcn_mfma_f32_16x16x32_bf16(ak1, bq[tg][1], a, 0, 0, 0);
        S[tg][nt] = a;
      }
    }

    // bias + exp2. Saturation: all |s-t| >= 128 in tile -> constant bias (exact bucket clamp).
    const int drel = s0 - t0w;         // wave-uniform
    if (drel >= 160 || drel <= -192){
      const float sv = (drel > 0) ? tabh[1151] : tabh[895];   // rp=+128 / rp=-128 saturated values
      #pragma unroll
      for (int tg = 0; tg < 2; tg++){
        const float cb = g[tg] * sv;
        #pragma unroll
        for (int nt = 0; nt < 4; nt++)
          #pragma unroll
          for (int r = 0; r < 4; r++)
            S[tg][nt][r] = __builtin_amdgcn_exp2f(S[tg][nt][r] + cb);
      }
    } else {
      #pragma unroll
      for (int tg = 0; tg < 2; tg++){
        const int ib = ibase[tg] + s0;
        #pragma unroll
        for (int nt = 0; nt < 4; nt++)
          #pragma unroll
          for (int r = 0; r < 4; r++)
            S[tg][nt][r] = __builtin_amdgcn_exp2f(S[tg][nt][r] + g[tg] * tabh[ib + nt * 16 + quad * 4 + r]);
      }
    }

    // P^T -> wave-local LDS (t-major); denominator off critical path
    #pragma unroll
    for (int tg = 0; tg < 2; tg++){
      __bf16* pw = &Pt[wid][tg][0];
      #pragma unroll
      for (int nt = 0; nt < 4; nt++){
        bf16x4 p;
        p[0] = f2bf_fast(S[tg][nt][0]); p[1] = f2bf_fast(S[tg][nt][1]);
        p[2] = f2bf_fast(S[tg][nt][2]); p[3] = f2bf_fast(S[tg][nt][3]);
        *(bf16x4*)&pw[l15 * LDP + nt * 16 + quad * 4] = p;
      }
      float rs = 0.f;
      #pragma unroll
      for (int nt = 0; nt < 4; nt++) rs += (S[tg][nt][0] + S[tg][nt][1]) + (S[tg][nt][2] + S[tg][nt][3]);
      rs += __shfl_xor(rs, 16, 64);
      rs += __shfl_xor(rs, 32, 64);
      l_run[tg] += rs;
    }

    // O^T += V^T.P^T: A=V^T (shared across tg, swizzled), B=P^T
    #pragma unroll
    for (int ks = 0; ks < 2; ks++){
      bf16x8 bp[2];
      #pragma unroll
      for (int tg = 0; tg < 2; tg++)
        bp[tg] = *(const bf16x8*)&Pt[wid][tg][l15 * LDP + ks * 32 + quad * 8];
      #pragma unroll
      for (int mt = 0; mt < 4; mt++){
        const int rowb = (mt * 16 + l15) * 64;
        bf16x8 av = *(const bf16x8*)&Vt[rowb + (((ks * 4 + quad) ^ swf) * 8)];
        #pragma unroll
        for (int tg = 0; tg < 2; tg++)
          O[tg][mt] = __builtin_amdgcn_mfma_f32_16x16x32_bf16(av, bp[tg], O[tg][mt], 0, 0, 0);
      }
    }
  }

  // epilogue: ctx[(t*B+b)*E + h*64+d], d = mt*16+quad*4+r
  #pragma unroll
  for (int tg = 0; tg < 2; tg++){
    const int t_lane = t0w + tg * 16 + l15;
    const float inv = 1.f / l_run[tg];
    #pragma unroll
    for (int mt = 0; mt < 4; mt++){
      bf16x4 o;
      o[0] = f2bf(O[tg][mt][0] * inv); o[1] = f2bf(O[tg][mt][1] * inv);
      o[2] = f2bf(O[tg][mt][2] * inv); o[3] = f2bf(O[tg][mt][3] * inv);
      *(bf16x4*)&ctx[(size_t)(t_lane * B_ + b) * E_ + h * DH_ + mt * 16 + quad * 4] = o;
    }
  }
}

extern "C" void kernel_launch(void* const* d_in, const int* in_sizes, int n_in,
                              void* d_out, int out_size, void* d_ws, size_t ws_size,
                              hipStream_t stream)
{
  (void)in_sizes; (void)n_in; (void)out_size; (void)ws_size;
  const float* query    = (const float*)d_in[0];
  const float* q_w      = (const float*)d_in[1];
  const float* q_b      = (const float*)d_in[2];
  const float* k_w      = (const float*)d_in[3];
  const float* k_b      = (const float*)d_in[4];
  const float* v_w      = (const float*)d_in[5];
  const float* v_b      = (const float*)d_in[6];
  const float* out_w    = (const float*)d_in[7];
  const float* out_b    = (const float*)d_in[8];
  const float* rel_bias = (const float*)d_in[9];
  const float* grep_w   = (const float*)d_in[10];
  const float* grep_b   = (const float*)d_in[11];
  const float* grep_a   = (const float*)d_in[12];

  char* ws = (char*)d_ws;
  size_t off = 0;
  __bf16* qbf = (__bf16*)(ws + off); off += (size_t)4096 * 1024 * 2;   // query bf16 (TB, E)
  __bf16* wq  = (__bf16*)(ws + off); off += (size_t)1024 * 1024 * 2;
  __bf16* wk  = (__bf16*)(ws + off); off += (size_t)1024 * 1024 * 2;
  __bf16* wv  = (__bf16*)(ws + off); off += (size_t)1024 * 1024 * 2;
  __bf16* wo  = (__bf16*)(ws + off); off += (size_t)1024 * 1024 * 2;
  __bf16* qh  = (__bf16*)(ws + off); off += (size_t)4096 * 1024 * 2;   // (B,H,T,DH)
  __bf16* kh  = (__bf16*)(ws + off); off += (size_t)4096 * 1024 * 2;   // (B,H,T,DH)
  __bf16* vhT = (__bf16*)(ws + off); off += (size_t)4096 * 1024 * 2;   // (B,H,DH,T)
  __bf16* ctx = (__bf16*)(ws + off); off += (size_t)4096 * 1024 * 2;   // (TB, E)
  float* gates = (float*)(ws + off); off += (size_t)65536 * 4;         // (B*H, T), * log2e
  float* tab   = (float*)(ws + off); off += (size_t)16 * 2047 * 4;     // (H, 2047) fp32

  prep_kernel<<<4480, 256, 0, stream>>>(q_w, k_w, v_w, out_w, wq, wk, wv, wo,
                                        query, grep_w, grep_b, grep_a, gates, qbf,
                                        rel_bias, tab);
  gemm_qkv<<<512, 256, 0, stream>>>(qbf, wq, wk, wv, q_b, k_b, v_b, qh, kh, vhT);
  attn_kernel<<<1024, 128, 0, stream>>>(qh, kh, vhT, gates, tab, ctx);
  gemm_out<<<512, 256, 0, stream>>>(ctx, wo, out_b, (float*)d_out);
}